// Round 1
// baseline (10867.437 us; speedup 1.0000x reference)
//
#include <hip/hip_runtime.h>

typedef unsigned short USH;
typedef unsigned int u32;
typedef float v4f __attribute__((ext_vector_type(4)));
typedef __bf16 v8bf __attribute__((ext_vector_type(8)));

#define B_ 64
#define T_ 512
#define E_ 512
#define H_ 1024

__device__ __forceinline__ USH f2b(float x) {
  union { float f; u32 u; } v; v.f = x;
  u32 r = v.u + 0x7FFFu + ((v.u >> 16) & 1u);
  return (USH)(r >> 16);
}
__device__ __forceinline__ v8bf ldb8(const USH* p) {
  uint4 u = *reinterpret_cast<const uint4*>(p);
  return __builtin_bit_cast(v8bf, u);
}
__device__ __forceinline__ v4f MF(v8bf a, v8bf b, v4f c) {
  return __builtin_amdgcn_mfma_f32_16x16x32_bf16(a, b, c, 0, 0, 0);
}
__device__ __forceinline__ float sigm(float x) { return 1.0f / (1.0f + __expf(-x)); }
__device__ __forceinline__ float tanhx(float x) { return 1.0f - 2.0f / (__expf(2.0f * x) + 1.0f); }

// ---------------- f32 -> bf16 cast ----------------
__global__ void castk(const float* __restrict__ s, USH* __restrict__ d, int n) {
  int i = (blockIdx.x * 256 + threadIdx.x) * 4;
  if (i >= n) return;
  float4 v = *reinterpret_cast<const float4*>(s + i);
  ushort4 q = make_ushort4(f2b(v.x), f2b(v.y), f2b(v.z), f2b(v.w));
  *reinterpret_cast<ushort4*>(d + i) = q;
}

// ---------------- embedding gather (-> bf16) ----------------
__global__ void gatherk(const int* __restrict__ x, const float* __restrict__ emb, USH* __restrict__ xeb) {
  int r = blockIdx.x;                       // r = b*T + t
  int id = x[r];
  const float4* e = reinterpret_cast<const float4*>(emb + (long)id * E_);
  float4 v = e[threadIdx.x];                // 128 threads * 4 floats = 512
  ushort4 q = make_ushort4(f2b(v.x), f2b(v.y), f2b(v.z), f2b(v.w));
  *reinterpret_cast<ushort4*>(xeb + (long)r * E_ + threadIdx.x * 4) = q;
}

// ---------------- persistent GRU scan ----------------
// grid = 128 blocks: bg = blk>>6 (batch group of 32), cb = blk&63 (16 h-columns)
// waves split K 4-way; weights LDS-resident (swizzled); per-group 64-block spin barrier.
__global__ __launch_bounds__(256, 1) void gru_scan(
    const USH* __restrict__ xeb, const USH* __restrict__ wihB, const USH* __restrict__ whhB,
    const float* __restrict__ bih, const float* __restrict__ bhh,
    USH* __restrict__ hg, u32* __restrict__ bar, USH* __restrict__ hs)
{
  __shared__ USH wih_s[48 * 512];     // 48KB
  __shared__ USH whh_s[48 * 1024];    // 96KB
  __shared__ float red[3 * 256 * 4];  // 12KB reduction buffer

  const int tid = threadIdx.x;
  const int wv = tid >> 6, ln = tid & 63;
  const int l16 = ln & 15, lq = ln >> 4;
  const int bg = blockIdx.x >> 6, cb = blockIdx.x & 63;
  const int b0 = bg * 32, c0 = cb * 16;

  // load weight slices into LDS, 16B-chunk XOR swizzle (chunk ^= row&7)
  for (int i = tid; i < 48 * 64; i += 256) {
    int row = i >> 6, ch = i & 63;
    int g = (row >> 4) * H_ + c0 + (row & 15);
    uint4 v = *reinterpret_cast<const uint4*>(wihB + g * E_ + ch * 8);
    *reinterpret_cast<uint4*>(wih_s + row * E_ + ((ch ^ (row & 7)) << 3)) = v;
  }
  for (int i = tid; i < 48 * 128; i += 256) {
    int row = i >> 7, ch = i & 127;
    int g = (row >> 4) * H_ + c0 + (row & 15);
    uint4 v = *reinterpret_cast<const uint4*>(whhB + g * H_ + ch * 8);
    *reinterpret_cast<uint4*>(whh_s + row * H_ + ((ch ^ (row & 7)) << 3)) = v;
  }
  __syncthreads();

  const int cgl = c0 + l16;
  const float bir = bih[cgl], biz = bih[H_ + cgl], bin = bih[2 * H_ + cgl];
  const float bhr = bhh[cgl], bhz = bhh[H_ + cgl], bhn = bhh[2 * H_ + cgl];

  const USH* a1b = xeb + (b0 + l16) * (T_ * E_) + wv * 128 + 8 * lq;
  const USH* a2b = hg + (b0 + l16) * H_ + wv * 256 + 8 * lq;
  u32* barp = bar + bg * 32;

  float hp[8];
  #pragma unroll
  for (int i = 0; i < 8; ++i) hp[i] = 0.f;

  v4f* rv = reinterpret_cast<v4f*>(red);
  const v4f z4 = {0.f, 0.f, 0.f, 0.f};

  for (int t = 0; t < T_; ++t) {
    v4f acc[8];  // 0/1:R(m0,m1) 2/3:Z 4/5:NI 6/7:NH
    #pragma unroll
    for (int i = 0; i < 8; ++i) acc[i] = z4;

    // ---- phase 1: xe_t @ w_ih^T (independent of barrier) ----
    const USH* a1 = a1b + t * E_;
    #pragma unroll
    for (int kt = 0; kt < 4; ++kt) {
      v8bf a0 = ldb8(a1 + kt * 32);
      v8bf a1f = ldb8(a1 + 16 * (T_ * E_) + kt * 32);
      int ch = wv * 16 + kt * 4 + lq;
      int rR = l16, rZ = 16 + l16, rN = 32 + l16;
      v8bf bR = ldb8(wih_s + rR * E_ + ((ch ^ (rR & 7)) << 3));
      v8bf bZ = ldb8(wih_s + rZ * E_ + ((ch ^ (rZ & 7)) << 3));
      v8bf bN = ldb8(wih_s + rN * E_ + ((ch ^ (rN & 7)) << 3));
      acc[0] = MF(a0, bR, acc[0]); acc[1] = MF(a1f, bR, acc[1]);
      acc[2] = MF(a0, bZ, acc[2]); acc[3] = MF(a1f, bZ, acc[3]);
      acc[4] = MF(a0, bN, acc[4]); acc[5] = MF(a1f, bN, acc[5]);
    }

    // ---- wait for h_{t-1} from the whole group ----
    if (t > 0) {
      if (tid == 0) {
        u32 tgt = (u32)(64 * t);
        while (__hip_atomic_load(barp, __ATOMIC_ACQUIRE, __HIP_MEMORY_SCOPE_AGENT) < tgt)
          __builtin_amdgcn_s_sleep(1);
      }
      __syncthreads();
      __threadfence();
    }

    // ---- phase 2: h_{t-1} @ w_hh^T ----
    const USH* a2 = a2b + ((t & 1) ^ 1) * (B_ * H_);
    #pragma unroll
    for (int kt = 0; kt < 8; ++kt) {
      v8bf a0 = ldb8(a2 + kt * 32);
      v8bf a1f = ldb8(a2 + 16 * H_ + kt * 32);
      int ch = wv * 32 + kt * 4 + lq;
      int rR = l16, rZ = 16 + l16, rN = 32 + l16;
      v8bf bR = ldb8(whh_s + rR * H_ + ((ch ^ (rR & 7)) << 3));
      v8bf bZ = ldb8(whh_s + rZ * H_ + ((ch ^ (rZ & 7)) << 3));
      v8bf bN = ldb8(whh_s + rN * H_ + ((ch ^ (rN & 7)) << 3));
      acc[0] = MF(a0, bR, acc[0]); acc[1] = MF(a1f, bR, acc[1]);
      acc[2] = MF(a0, bZ, acc[2]); acc[3] = MF(a1f, bZ, acc[3]);
      acc[6] = MF(a0, bN, acc[6]); acc[7] = MF(a1f, bN, acc[7]);
    }

    // ---- cross-wave reduction (two 12KB rounds) ----
    if (wv != 0) {
      #pragma unroll
      for (int f = 0; f < 4; ++f) rv[(wv - 1) * 256 + f * 64 + ln] = acc[f];
    }
    __syncthreads();
    if (wv == 0) {
      #pragma unroll
      for (int w = 0; w < 3; ++w) {
        #pragma unroll
        for (int f = 0; f < 4; ++f) acc[f] += rv[w * 256 + f * 64 + ln];
      }
    }
    __syncthreads();
    if (wv != 0) {
      #pragma unroll
      for (int f = 0; f < 4; ++f) rv[(wv - 1) * 256 + f * 64 + ln] = acc[4 + f];
    }
    __syncthreads();
    if (wv == 0) {
      #pragma unroll
      for (int w = 0; w < 3; ++w) {
        #pragma unroll
        for (int f = 0; f < 4; ++f) acc[4 + f] += rv[w * 256 + f * 64 + ln];
      }
      // ---- gates + state update (wave0 owns this block's (b,c) outputs) ----
      USH* hw = hg + (t & 1) * (B_ * H_);
      USH* hst = hs + t * (B_ * H_);
      #pragma unroll
      for (int mm = 0; mm < 2; ++mm) {
        #pragma unroll
        for (int r4 = 0; r4 < 4; ++r4) {
          int b = b0 + mm * 16 + lq * 4 + r4;
          float rg = sigm(acc[0 + mm][r4] + bir + bhr);
          float zg = sigm(acc[2 + mm][r4] + biz + bhz);
          float ng = tanhx(acc[4 + mm][r4] + bin + rg * (acc[6 + mm][r4] + bhn));
          int hi = mm * 4 + r4;
          float hn = (1.f - zg) * ng + zg * hp[hi];
          hp[hi] = hn;
          USH hb = f2b(hn);
          hw[b * H_ + cgl] = hb;
          hst[b * H_ + cgl] = hb;
        }
      }
      __threadfence();
      if (ln == 0) __hip_atomic_fetch_add(barp, 1u, __ATOMIC_RELEASE, __HIP_MEMORY_SCOPE_AGENT);
    }
  }
}

// ---------------- emissions: em[b,t,k] = hs[t,b,:] . fc_w[k,:] + fc_b[k] ----------------
__global__ __launch_bounds__(256) void emisk(const USH* __restrict__ hs, const USH* __restrict__ fcwB,
                                             const float* __restrict__ fcb, float* __restrict__ em) {
  __shared__ float red[3 * 256 * 4];
  int t = blockIdx.x >> 2, bq = blockIdx.x & 3;
  int tid = threadIdx.x, wv = tid >> 6, ln = tid & 63, l16 = ln & 15, lq = ln >> 4;
  int b0 = bq * 16;
  const USH* ab = hs + (t * 64 + b0 + l16) * H_ + wv * 256 + 8 * lq;
  const v4f z4 = {0.f, 0.f, 0.f, 0.f};
  v4f acc[4];
  #pragma unroll
  for (int i = 0; i < 4; ++i) acc[i] = z4;
  #pragma unroll
  for (int kt = 0; kt < 8; ++kt) {
    v8bf a = ldb8(ab + kt * 32);
    #pragma unroll
    for (int nt = 0; nt < 4; ++nt) {
      const USH* bp = fcwB + (nt * 16 + l16) * H_ + wv * 256 + kt * 32 + 8 * lq;
      acc[nt] = MF(a, ldb8(bp), acc[nt]);
    }
  }
  v4f* rv = reinterpret_cast<v4f*>(red);
  if (wv != 0) {
    #pragma unroll
    for (int nt = 0; nt < 4; ++nt) rv[(wv - 1) * 256 + nt * 64 + ln] = acc[nt];
  }
  __syncthreads();
  if (wv == 0) {
    #pragma unroll
    for (int nt = 0; nt < 4; ++nt) {
      v4f s = acc[nt];
      #pragma unroll
      for (int w = 0; w < 3; ++w) s += rv[w * 256 + nt * 64 + ln];
      int k = nt * 16 + l16;
      float bias = fcb[k];
      #pragma unroll
      for (int r = 0; r < 4; ++r) {
        int b = b0 + lq * 4 + r;
        em[(b * T_ + t) * 64 + k] = s[r] + bias;
      }
    }
  }
}

// ---------------- CRF NLL per batch element ----------------
__global__ __launch_bounds__(64) void crfk(const float* __restrict__ em, const int* __restrict__ tags,
                                           const float* __restrict__ st, const float* __restrict__ en,
                                           const float* __restrict__ tr, float* __restrict__ res) {
  int b = blockIdx.x, j = threadIdx.x;
  __shared__ float trs[4096];
  for (int i = j; i < 4096; i += 64) trs[i] = tr[i];
  __syncthreads();
  const int* tg = tags + b * T_;
  const float* e = em + (long)b * T_ * 64;
  // numerator (gold path score), t-parallel
  float np = 0.f;
  for (int t = j; t < T_; t += 64) {
    int ct = tg[t];
    np += e[t * 64 + ct];
    if (t > 0) np += trs[tg[t - 1] * 64 + ct];
  }
  #pragma unroll
  for (int o = 32; o; o >>= 1) np += __shfl_xor(np, o, 64);
  float num = np + st[tg[0]] + en[tg[T_ - 1]];
  // forward algorithm; lane j holds alpha[j]
  float alpha = st[j] + e[j];
  for (int t = 1; t < T_; ++t) {
    float m = -3.4e38f;
    #pragma unroll 8
    for (int i = 0; i < 64; ++i) {
      float v = __shfl(alpha, i, 64) + trs[i * 64 + j];
      m = fmaxf(m, v);
    }
    float s = 0.f;
    #pragma unroll 8
    for (int i = 0; i < 64; ++i) {
      float v = __shfl(alpha, i, 64) + trs[i * 64 + j];
      s += __expf(v - m);
    }
    alpha = m + __logf(s) + e[t * 64 + j];
  }
  float v = alpha + en[j];
  float mm = v;
  #pragma unroll
  for (int o = 32; o; o >>= 1) mm = fmaxf(mm, __shfl_xor(mm, o, 64));
  float ss = __expf(v - mm);
  #pragma unroll
  for (int o = 32; o; o >>= 1) ss += __shfl_xor(ss, o, 64);
  if (j == 0) res[b] = (mm + __logf(ss)) - num;
}

__global__ void fin(const float* __restrict__ res, float* __restrict__ out) {
  float v = res[threadIdx.x];
  #pragma unroll
  for (int o = 32; o; o >>= 1) v += __shfl_xor(v, o, 64);
  if (threadIdx.x == 0) out[0] = v;
}

extern "C" void kernel_launch(void* const* d_in, const int* in_sizes, int n_in,
                              void* d_out, int out_size, void* d_ws, size_t ws_size,
                              hipStream_t stream) {
  (void)in_sizes; (void)n_in; (void)out_size;
  const int*   x    = (const int*)d_in[0];
  const int*   tags = (const int*)d_in[1];
  const float* emb  = (const float*)d_in[2];
  const float* wih  = (const float*)d_in[3];
  const float* whh  = (const float*)d_in[4];
  const float* bih  = (const float*)d_in[5];
  const float* bhh  = (const float*)d_in[6];
  const float* fcw  = (const float*)d_in[7];
  const float* fcb  = (const float*)d_in[8];
  const float* str  = (const float*)d_in[9];
  const float* enr  = (const float*)d_in[10];
  const float* trn  = (const float*)d_in[11];

  char* ws = (char*)d_ws;
  // workspace layout (bytes)
  USH*   xeb  = (USH*)(ws + 0);           // 33,554,432
  USH*   wihB = (USH*)(ws + 33554432);    //  3,145,728
  USH*   whhB = (USH*)(ws + 36700160);    //  6,291,456
  USH*   fcwB = (USH*)(ws + 42991616);    //    131,072
  USH*   hg   = (USH*)(ws + 43122688);    //    262,144 (2 x [64][1024] bf16)
  u32*   bar  = (u32*)(ws + 43384832);    //        256 (2 counters, 128B apart)
  USH*   hs   = (USH*)(ws + 43385088);    // 67,108,864 ([T][B][H] bf16)
  float* em   = (float*)(ws + 110493952); //  8,388,608 ([B][T][64] f32)
  float* res  = (float*)(ws + 118882560); //        256
  if (ws_size < 118882816ull) return;

  // zero h double-buffer + barrier counters (runs every call / every replay)
  hipMemsetAsync(ws + 43122688, 0, 262400, stream);

  castk<<<1536, 256, 0, stream>>>(wih, wihB, 3 * H_ * E_);
  castk<<<3072, 256, 0, stream>>>(whh, whhB, 3 * H_ * H_);
  castk<<<64, 256, 0, stream>>>(fcw, fcwB, 64 * H_);
  gatherk<<<B_ * T_, 128, 0, stream>>>(x, emb, xeb);
  gru_scan<<<128, 256, 0, stream>>>(xeb, wihB, whhB, bih, bhh, hg, bar, hs);
  emisk<<<T_ * 4, 256, 0, stream>>>(hs, fcwB, fcb, em);
  crfk<<<B_, 64, 0, stream>>>(em, tags, str, enr, trn, res);
  fin<<<1, 64, 0, stream>>>(res, (float*)d_out);
}

// Round 2
// 5764.120 us; speedup vs baseline: 1.8854x; 1.8854x over previous
//
#include <hip/hip_runtime.h>

typedef unsigned short USH;
typedef unsigned int u32;
typedef unsigned long long u64;
typedef float v4f __attribute__((ext_vector_type(4)));
typedef __bf16 v8bf __attribute__((ext_vector_type(8)));

#define B_ 64
#define T_ 512
#define E_ 512
#define H_ 1024

__device__ __forceinline__ USH f2b(float x) {
  union { float f; u32 u; } v; v.f = x;
  u32 r = v.u + 0x7FFFu + ((v.u >> 16) & 1u);
  return (USH)(r >> 16);
}
__device__ __forceinline__ v8bf ldb8(const USH* p) {
  uint4 u = *reinterpret_cast<const uint4*>(p);
  return __builtin_bit_cast(v8bf, u);
}
// cross-XCD coherent 16B load as 2x8B relaxed agent atomics (sc1 path, no cache maintenance)
__device__ __forceinline__ v8bf ldh8(const USH* p) {
  const u64* q = (const u64*)p;
  u64 lo = __hip_atomic_load(q, __ATOMIC_RELAXED, __HIP_MEMORY_SCOPE_AGENT);
  u64 hi = __hip_atomic_load(q + 1, __ATOMIC_RELAXED, __HIP_MEMORY_SCOPE_AGENT);
  union { u64 u[2]; v8bf v; } r; r.u[0] = lo; r.u[1] = hi;
  return r.v;
}
__device__ __forceinline__ void sth16(USH* p, uint4 v) {
  u64* q = (u64*)p;
  union { uint4 u4; u64 u[2]; } c; c.u4 = v;
  __hip_atomic_store(q, c.u[0], __ATOMIC_RELAXED, __HIP_MEMORY_SCOPE_AGENT);
  __hip_atomic_store(q + 1, c.u[1], __ATOMIC_RELAXED, __HIP_MEMORY_SCOPE_AGENT);
}
__device__ __forceinline__ v4f MF(v8bf a, v8bf b, v4f c) {
  return __builtin_amdgcn_mfma_f32_16x16x32_bf16(a, b, c, 0, 0, 0);
}
__device__ __forceinline__ float sigm(float x) { return 1.0f / (1.0f + __expf(-x)); }
__device__ __forceinline__ float tanhx(float x) { return 1.0f - 2.0f / (__expf(2.0f * x) + 1.0f); }

// ---------------- f32 -> bf16 cast ----------------
__global__ void castk(const float* __restrict__ s, USH* __restrict__ d, int n) {
  int i = (blockIdx.x * 256 + threadIdx.x) * 4;
  if (i >= n) return;
  float4 v = *reinterpret_cast<const float4*>(s + i);
  ushort4 q = make_ushort4(f2b(v.x), f2b(v.y), f2b(v.z), f2b(v.w));
  *reinterpret_cast<ushort4*>(d + i) = q;
}

// ---------------- embedding gather (-> bf16) ----------------
__global__ void gatherk(const int* __restrict__ x, const float* __restrict__ emb, USH* __restrict__ xeb) {
  int r = blockIdx.x;                       // r = b*T + t
  int id = x[r];
  const float4* e = reinterpret_cast<const float4*>(emb + (long)id * E_);
  float4 v = e[threadIdx.x];                // 128 threads * 4 floats = 512
  ushort4 q = make_ushort4(f2b(v.x), f2b(v.y), f2b(v.z), f2b(v.w));
  *reinterpret_cast<ushort4*>(xeb + (long)r * E_ + threadIdx.x * 4) = q;
}

// ---------------- persistent GRU scan ----------------
// grid = 128 blocks: bg = blk>>6 (batch group of 32), cb = blk&63 (16 h-columns)
// waves split K 4-way; weights LDS-resident (swizzled).
// Sync: per-(group, K-chunk) counters; relaxed agent atomics only (no L2 flush/inval).
__global__ __launch_bounds__(256, 1) void gru_scan(
    const USH* __restrict__ xeb, const USH* __restrict__ wihB, const USH* __restrict__ whhB,
    const float* __restrict__ bih, const float* __restrict__ bhh,
    USH* __restrict__ hg, u32* __restrict__ bar, USH* __restrict__ hs)
{
  __shared__ USH wih_s[48 * 512];     // 48KB
  __shared__ USH whh_s[48 * 1024];    // 96KB
  __shared__ float red[3 * 256 * 4];  // 12KB reduction buffer
  __shared__ USH tr[32][16];          // 1KB h transpose (wave0 only)

  const int tid = threadIdx.x;
  const int wv = tid >> 6, ln = tid & 63;
  const int l16 = ln & 15, lq = ln >> 4;
  const int bg = blockIdx.x >> 6, cb = blockIdx.x & 63;
  const int b0 = bg * 32, c0 = cb * 16;

  // load weight slices into LDS, 16B-chunk XOR swizzle (chunk ^= row&7)
  for (int i = tid; i < 48 * 64; i += 256) {
    int row = i >> 6, ch = i & 63;
    int g = (row >> 4) * H_ + c0 + (row & 15);
    uint4 v = *reinterpret_cast<const uint4*>(wihB + g * E_ + ch * 8);
    *reinterpret_cast<uint4*>(wih_s + row * E_ + ((ch ^ (row & 7)) << 3)) = v;
  }
  for (int i = tid; i < 48 * 128; i += 256) {
    int row = i >> 7, ch = i & 127;
    int g = (row >> 4) * H_ + c0 + (row & 15);
    uint4 v = *reinterpret_cast<const uint4*>(whhB + g * H_ + ch * 8);
    *reinterpret_cast<uint4*>(whh_s + row * H_ + ((ch ^ (row & 7)) << 3)) = v;
  }
  __syncthreads();

  const int cgl = c0 + l16;
  const float bir = bih[cgl], biz = bih[H_ + cgl], bin = bih[2 * H_ + cgl];
  const float bhr = bhh[cgl], bhz = bhh[H_ + cgl], bhn = bhh[2 * H_ + cgl];

  const USH* a1b = xeb + (b0 + l16) * (T_ * E_) + wv * 128 + 8 * lq;
  const USH* a2b = hg + (b0 + l16) * H_ + wv * 256 + 8 * lq;
  // counters: [group][chunk], 128B apart. wave wv waits on chunk wv; block cb increments chunk cb>>4.
  u32* mycnt = bar + (bg * 4 + wv) * 32;
  u32* wrcnt = bar + (bg * 4 + (cb >> 4)) * 32;

  float hp[8];
  #pragma unroll
  for (int i = 0; i < 8; ++i) hp[i] = 0.f;

  v4f* rv = reinterpret_cast<v4f*>(red);
  const v4f z4 = {0.f, 0.f, 0.f, 0.f};

  for (int t = 0; t < T_; ++t) {
    v4f acc[8];  // 0/1:R(m0,m1) 2/3:Z 4/5:NI 6/7:NH
    #pragma unroll
    for (int i = 0; i < 8; ++i) acc[i] = z4;

    // ---- phase 1: xe_t @ w_ih^T (independent of the recurrence) ----
    const USH* a1 = a1b + t * E_;
    #pragma unroll
    for (int kt = 0; kt < 4; ++kt) {
      v8bf a0 = ldb8(a1 + kt * 32);
      v8bf a1f = ldb8(a1 + 16 * (T_ * E_) + kt * 32);
      int ch = wv * 16 + kt * 4 + lq;
      int rR = l16, rZ = 16 + l16, rN = 32 + l16;
      v8bf bR = ldb8(wih_s + rR * E_ + ((ch ^ (rR & 7)) << 3));
      v8bf bZ = ldb8(wih_s + rZ * E_ + ((ch ^ (rZ & 7)) << 3));
      v8bf bN = ldb8(wih_s + rN * E_ + ((ch ^ (rN & 7)) << 3));
      acc[0] = MF(a0, bR, acc[0]); acc[1] = MF(a1f, bR, acc[1]);
      acc[2] = MF(a0, bZ, acc[2]); acc[3] = MF(a1f, bZ, acc[3]);
      acc[4] = MF(a0, bN, acc[4]); acc[5] = MF(a1f, bN, acc[5]);
    }

    // ---- per-wave wait: only the 16 producer blocks of my K-chunk ----
    if (t > 0) {
      u32 tgt = (u32)(16 * t);
      if (ln == 0) {  // whole wave is held by lane0's masked spin
        while (__hip_atomic_load(mycnt, __ATOMIC_RELAXED, __HIP_MEMORY_SCOPE_AGENT) < tgt)
          __builtin_amdgcn_s_sleep(1);
      }
    }

    // ---- phase 2: h_{t-1} @ w_hh^T (h via coherent sc1 loads) ----
    const USH* a2 = a2b + ((t & 1) ^ 1) * (B_ * H_);
    #pragma unroll
    for (int kt = 0; kt < 8; ++kt) {
      v8bf a0 = ldh8(a2 + kt * 32);
      v8bf a1f = ldh8(a2 + 16 * H_ + kt * 32);
      int ch = wv * 32 + kt * 4 + lq;
      int rR = l16, rZ = 16 + l16, rN = 32 + l16;
      v8bf bR = ldb8(whh_s + rR * H_ + ((ch ^ (rR & 7)) << 3));
      v8bf bZ = ldb8(whh_s + rZ * H_ + ((ch ^ (rZ & 7)) << 3));
      v8bf bN = ldb8(whh_s + rN * H_ + ((ch ^ (rN & 7)) << 3));
      acc[0] = MF(a0, bR, acc[0]); acc[1] = MF(a1f, bR, acc[1]);
      acc[2] = MF(a0, bZ, acc[2]); acc[3] = MF(a1f, bZ, acc[3]);
      acc[6] = MF(a0, bN, acc[6]); acc[7] = MF(a1f, bN, acc[7]);
    }

    // ---- cross-wave reduction (two 12KB rounds) ----
    if (wv != 0) {
      #pragma unroll
      for (int f = 0; f < 4; ++f) rv[(wv - 1) * 256 + f * 64 + ln] = acc[f];
    }
    __syncthreads();
    if (wv == 0) {
      #pragma unroll
      for (int w = 0; w < 3; ++w) {
        #pragma unroll
        for (int f = 0; f < 4; ++f) acc[f] += rv[w * 256 + f * 64 + ln];
      }
    }
    __syncthreads();
    if (wv != 0) {
      #pragma unroll
      for (int f = 0; f < 4; ++f) rv[(wv - 1) * 256 + f * 64 + ln] = acc[4 + f];
    }
    __syncthreads();
    if (wv == 0) {
      #pragma unroll
      for (int w = 0; w < 3; ++w) {
        #pragma unroll
        for (int f = 0; f < 4; ++f) acc[4 + f] += rv[w * 256 + f * 64 + ln];
      }
      // ---- gates + state update (wave0 owns this block's (b,c) outputs) ----
      #pragma unroll
      for (int mm = 0; mm < 2; ++mm) {
        #pragma unroll
        for (int r4 = 0; r4 < 4; ++r4) {
          float rg = sigm(acc[0 + mm][r4] + bir + bhr);
          float zg = sigm(acc[2 + mm][r4] + biz + bhz);
          float ng = tanhx(acc[4 + mm][r4] + bin + rg * (acc[6 + mm][r4] + bhn));
          int hi = mm * 4 + r4;
          float hn = (1.f - zg) * ng + zg * hp[hi];
          hp[hi] = hn;
          tr[mm * 16 + lq * 4 + r4][l16] = f2b(hn);   // LDS transpose
        }
      }
      // read back one 16B row-segment per lane: row = ln>>1, half = ln&1
      {
        int row = ln >> 1, half = ln & 1;
        uint4 hv = *reinterpret_cast<const uint4*>(&tr[row][half * 8]);
        int b = b0 + row;
        USH* dsth = hg + (t & 1) * (B_ * H_) + b * H_ + c0 + half * 8;
        sth16(dsth, hv);                                           // coherent store for next step
        *reinterpret_cast<uint4*>(hs + (long)t * (B_ * H_) + b * H_ + c0 + half * 8) = hv;  // history (plain)
      }
      asm volatile("s_waitcnt vmcnt(0)" ::: "memory");  // h stores device-visible (sc1 path)
      if (ln == 0) __hip_atomic_fetch_add(wrcnt, 1u, __ATOMIC_RELAXED, __HIP_MEMORY_SCOPE_AGENT);
    }
  }
}

// ---------------- emissions: em[b,t,k] = hs[t,b,:] . fc_w[k,:] + fc_b[k] ----------------
__global__ __launch_bounds__(256) void emisk(const USH* __restrict__ hs, const USH* __restrict__ fcwB,
                                             const float* __restrict__ fcb, float* __restrict__ em) {
  __shared__ float red[3 * 256 * 4];
  int t = blockIdx.x >> 2, bq = blockIdx.x & 3;
  int tid = threadIdx.x, wv = tid >> 6, ln = tid & 63, l16 = ln & 15, lq = ln >> 4;
  int b0 = bq * 16;
  const USH* ab = hs + (t * 64 + b0 + l16) * H_ + wv * 256 + 8 * lq;
  const v4f z4 = {0.f, 0.f, 0.f, 0.f};
  v4f acc[4];
  #pragma unroll
  for (int i = 0; i < 4; ++i) acc[i] = z4;
  #pragma unroll
  for (int kt = 0; kt < 8; ++kt) {
    v8bf a = ldb8(ab + kt * 32);
    #pragma unroll
    for (int nt = 0; nt < 4; ++nt) {
      const USH* bp = fcwB + (nt * 16 + l16) * H_ + wv * 256 + kt * 32 + 8 * lq;
      acc[nt] = MF(a, ldb8(bp), acc[nt]);
    }
  }
  v4f* rv = reinterpret_cast<v4f*>(red);
  if (wv != 0) {
    #pragma unroll
    for (int nt = 0; nt < 4; ++nt) rv[(wv - 1) * 256 + nt * 64 + ln] = acc[nt];
  }
  __syncthreads();
  if (wv == 0) {
    #pragma unroll
    for (int nt = 0; nt < 4; ++nt) {
      v4f s = acc[nt];
      #pragma unroll
      for (int w = 0; w < 3; ++w) s += rv[w * 256 + nt * 64 + ln];
      int k = nt * 16 + l16;
      float bias = fcb[k];
      #pragma unroll
      for (int r = 0; r < 4; ++r) {
        int b = b0 + lq * 4 + r;
        em[(b * T_ + t) * 64 + k] = s[r] + bias;
      }
    }
  }
}

// ---------------- CRF NLL per batch element ----------------
__global__ __launch_bounds__(64) void crfk(const float* __restrict__ em, const int* __restrict__ tags,
                                           const float* __restrict__ st, const float* __restrict__ en,
                                           const float* __restrict__ tr, float* __restrict__ res) {
  int b = blockIdx.x, j = threadIdx.x;
  __shared__ float trs[4096];
  for (int i = j; i < 4096; i += 64) trs[i] = tr[i];
  __syncthreads();
  const int* tg = tags + b * T_;
  const float* e = em + (long)b * T_ * 64;
  // numerator (gold path score), t-parallel
  float np = 0.f;
  for (int t = j; t < T_; t += 64) {
    int ct = tg[t];
    np += e[t * 64 + ct];
    if (t > 0) np += trs[tg[t - 1] * 64 + ct];
  }
  #pragma unroll
  for (int o = 32; o; o >>= 1) np += __shfl_xor(np, o, 64);
  float num = np + st[tg[0]] + en[tg[T_ - 1]];
  // forward algorithm; lane j holds alpha[j]
  float alpha = st[j] + e[j];
  for (int t = 1; t < T_; ++t) {
    float m = -3.4e38f;
    #pragma unroll 8
    for (int i = 0; i < 64; ++i) {
      float v = __shfl(alpha, i, 64) + trs[i * 64 + j];
      m = fmaxf(m, v);
    }
    float s = 0.f;
    #pragma unroll 8
    for (int i = 0; i < 64; ++i) {
      float v = __shfl(alpha, i, 64) + trs[i * 64 + j];
      s += __expf(v - m);
    }
    alpha = m + __logf(s) + e[t * 64 + j];
  }
  float v = alpha + en[j];
  float mm = v;
  #pragma unroll
  for (int o = 32; o; o >>= 1) mm = fmaxf(mm, __shfl_xor(mm, o, 64));
  float ss = __expf(v - mm);
  #pragma unroll
  for (int o = 32; o; o >>= 1) ss += __shfl_xor(ss, o, 64);
  if (j == 0) res[b] = (mm + __logf(ss)) - num;
}

__global__ void fin(const float* __restrict__ res, float* __restrict__ out) {
  float v = res[threadIdx.x];
  #pragma unroll
  for (int o = 32; o; o >>= 1) v += __shfl_xor(v, o, 64);
  if (threadIdx.x == 0) out[0] = v;
}

extern "C" void kernel_launch(void* const* d_in, const int* in_sizes, int n_in,
                              void* d_out, int out_size, void* d_ws, size_t ws_size,
                              hipStream_t stream) {
  (void)in_sizes; (void)n_in; (void)out_size;
  const int*   x    = (const int*)d_in[0];
  const int*   tags = (const int*)d_in[1];
  const float* emb  = (const float*)d_in[2];
  const float* wih  = (const float*)d_in[3];
  const float* whh  = (const float*)d_in[4];
  const float* bih  = (const float*)d_in[5];
  const float* bhh  = (const float*)d_in[6];
  const float* fcw  = (const float*)d_in[7];
  const float* fcb  = (const float*)d_in[8];
  const float* str  = (const float*)d_in[9];
  const float* enr  = (const float*)d_in[10];
  const float* trn  = (const float*)d_in[11];

  char* ws = (char*)d_ws;
  // workspace layout (bytes) — same footprint as round 1
  USH*   xeb  = (USH*)(ws + 0);           // 33,554,432
  USH*   wihB = (USH*)(ws + 33554432);    //  3,145,728
  USH*   whhB = (USH*)(ws + 36700160);    //  6,291,456
  USH*   fcwB = (USH*)(ws + 42991616);    //    131,072
  USH*   hg   = (USH*)(ws + 43122688);    //    262,144 (2 x [64][1024] bf16)
  USH*   hs   = (USH*)(ws + 43385088);    // 67,108,864 ([T][B][H] bf16)
  float* em   = (float*)(ws + 110493952); //  8,388,608 ([B][T][64] f32)
  u32*   bar  = (u32*)em;                 //  1,024 B: dead before emisk runs
  float* res  = (float*)(ws + 118882560); //        256
  if (ws_size < 118882816ull) return;

  // zero h double-buffer + barrier counters (runs every call / every replay)
  hipMemsetAsync(hg, 0, 262144, stream);
  hipMemsetAsync(bar, 0, 1024, stream);

  castk<<<1536, 256, 0, stream>>>(wih, wihB, 3 * H_ * E_);
  castk<<<3072, 256, 0, stream>>>(whh, whhB, 3 * H_ * H_);
  castk<<<64, 256, 0, stream>>>(fcw, fcwB, 64 * H_);
  gatherk<<<B_ * T_, 128, 0, stream>>>(x, emb, xeb);
  gru_scan<<<128, 256, 0, stream>>>(xeb, wihB, whhB, bih, bhh, hg, bar, hs);
  emisk<<<T_ * 4, 256, 0, stream>>>(hs, fcwB, fcb, em);
  crfk<<<B_, 64, 0, stream>>>(em, tags, str, enr, trn, res);
  fin<<<1, 64, 0, stream>>>(res, (float*)d_out);
}

// Round 3
// 4758.841 us; speedup vs baseline: 2.2836x; 1.2112x over previous
//
#include <hip/hip_runtime.h>

typedef unsigned short USH;
typedef unsigned int u32;
typedef unsigned long long u64;
typedef float v4f __attribute__((ext_vector_type(4)));
typedef __bf16 v8bf __attribute__((ext_vector_type(8)));

#define B_ 64
#define T_ 512
#define E_ 512
#define H_ 1024

__device__ __forceinline__ USH f2b(float x) {
  union { float f; u32 u; } v; v.f = x;
  u32 r = v.u + 0x7FFFu + ((v.u >> 16) & 1u);
  return (USH)(r >> 16);
}
__device__ __forceinline__ v8bf ldb8(const USH* p) {
  uint4 u = *reinterpret_cast<const uint4*>(p);
  return __builtin_bit_cast(v8bf, u);
}
// cross-XCD coherent 16B load as 2x8B relaxed agent atomics (bypasses stale L2)
__device__ __forceinline__ v8bf ldh8(const USH* p) {
  const u64* q = (const u64*)p;
  u64 lo = __hip_atomic_load(q, __ATOMIC_RELAXED, __HIP_MEMORY_SCOPE_AGENT);
  u64 hi = __hip_atomic_load(q + 1, __ATOMIC_RELAXED, __HIP_MEMORY_SCOPE_AGENT);
  union { u64 u[2]; v8bf v; } r; r.u[0] = lo; r.u[1] = hi;
  return r.v;
}
__device__ __forceinline__ void sth16(USH* p, uint4 v) {
  u64* q = (u64*)p;
  union { uint4 u4; u64 u[2]; } c; c.u4 = v;
  __hip_atomic_store(q, c.u[0], __ATOMIC_RELAXED, __HIP_MEMORY_SCOPE_AGENT);
  __hip_atomic_store(q + 1, c.u[1], __ATOMIC_RELAXED, __HIP_MEMORY_SCOPE_AGENT);
}
__device__ __forceinline__ v4f MF(v8bf a, v8bf b, v4f c) {
  return __builtin_amdgcn_mfma_f32_16x16x32_bf16(a, b, c, 0, 0, 0);
}
__device__ __forceinline__ float sigm(float x) { return 1.0f / (1.0f + __expf(-x)); }
__device__ __forceinline__ float tanhx(float x) { return 1.0f - 2.0f / (__expf(2.0f * x) + 1.0f); }

// ---------------- f32 -> bf16 cast ----------------
__global__ void castk(const float* __restrict__ s, USH* __restrict__ d, int n) {
  int i = (blockIdx.x * 256 + threadIdx.x) * 4;
  if (i >= n) return;
  float4 v = *reinterpret_cast<const float4*>(s + i);
  ushort4 q = make_ushort4(f2b(v.x), f2b(v.y), f2b(v.z), f2b(v.w));
  *reinterpret_cast<ushort4*>(d + i) = q;
}

// ---------------- embedding gather (-> bf16) ----------------
__global__ void gatherk(const int* __restrict__ x, const float* __restrict__ emb, USH* __restrict__ xeb) {
  int r = blockIdx.x;                       // r = b*T + t
  int id = x[r];
  const float4* e = reinterpret_cast<const float4*>(emb + (long)id * E_);
  float4 v = e[threadIdx.x];                // 128 threads * 4 floats = 512
  ushort4 q = make_ushort4(f2b(v.x), f2b(v.y), f2b(v.z), f2b(v.w));
  *reinterpret_cast<ushort4*>(xeb + (long)r * E_ + threadIdx.x * 4) = q;
}

// ---------------- persistent GRU scan ----------------
// grid = 128 blocks: bg = blk>>6 (batch group of 32), cb = blk&63 (16 h-columns)
// waves split K 4-way; weights LDS-resident (swizzled).
// Sync: per-BLOCK flag word on its own 64B line; store-only release, ballot-poll
// acquire (no RMWs anywhere on the wait path).
__global__ __launch_bounds__(256, 1) void gru_scan(
    const USH* __restrict__ xeb, const USH* __restrict__ wihB, const USH* __restrict__ whhB,
    const float* __restrict__ bih, const float* __restrict__ bhh,
    USH* __restrict__ hg, u32* __restrict__ flags, USH* __restrict__ hs)
{
  __shared__ USH wih_s[48 * 512];     // 48KB
  __shared__ USH whh_s[48 * 1024];    // 96KB
  __shared__ float red[3 * 256 * 4];  // 12KB reduction buffer
  __shared__ USH tr[32][16];          // 1KB h transpose (wave0 only)

  const int tid = threadIdx.x;
  const int wv = tid >> 6, ln = tid & 63;
  const int l16 = ln & 15, lq = ln >> 4;
  const int bg = blockIdx.x >> 6, cb = blockIdx.x & 63;
  const int b0 = bg * 32, c0 = cb * 16;

  // load weight slices into LDS, 16B-chunk XOR swizzle (chunk ^= row&7)
  for (int i = tid; i < 48 * 64; i += 256) {
    int row = i >> 6, ch = i & 63;
    int g = (row >> 4) * H_ + c0 + (row & 15);
    uint4 v = *reinterpret_cast<const uint4*>(wihB + g * E_ + ch * 8);
    *reinterpret_cast<uint4*>(wih_s + row * E_ + ((ch ^ (row & 7)) << 3)) = v;
  }
  for (int i = tid; i < 48 * 128; i += 256) {
    int row = i >> 7, ch = i & 127;
    int g = (row >> 4) * H_ + c0 + (row & 15);
    uint4 v = *reinterpret_cast<const uint4*>(whhB + g * H_ + ch * 8);
    *reinterpret_cast<uint4*>(whh_s + row * H_ + ((ch ^ (row & 7)) << 3)) = v;
  }
  __syncthreads();

  const int cgl = c0 + l16;
  const float bir = bih[cgl], biz = bih[H_ + cgl], bin = bih[2 * H_ + cgl];
  const float bhr = bhh[cgl], bhz = bhh[H_ + cgl], bhn = bhh[2 * H_ + cgl];

  const USH* a1b = xeb + (b0 + l16) * (T_ * E_) + wv * 128 + 8 * lq;
  const USH* a2b = hg + (b0 + l16) * H_ + wv * 256 + 8 * lq;
  u32* myflag = flags + (size_t)blockIdx.x * 16;                       // own 64B line
  const u32* wflag = flags + (size_t)(bg * 64 + wv * 16 + l16) * 16;   // my chunk's 16 producers

  float hp[8];
  #pragma unroll
  for (int i = 0; i < 8; ++i) hp[i] = 0.f;

  v4f* rv = reinterpret_cast<v4f*>(red);
  const v4f z4 = {0.f, 0.f, 0.f, 0.f};

  // prefetch xe A-fragments for t=0
  uint4 pf[8];
  #pragma unroll
  for (int kt = 0; kt < 4; ++kt) {
    pf[kt * 2]     = *reinterpret_cast<const uint4*>(a1b + kt * 32);
    pf[kt * 2 + 1] = *reinterpret_cast<const uint4*>(a1b + 16 * (T_ * E_) + kt * 32);
  }

  for (int t = 0; t < T_; ++t) {
    v4f acc[8];  // 0/1:R(m0,m1) 2/3:Z 4/5:NI 6/7:NH
    #pragma unroll
    for (int i = 0; i < 8; ++i) acc[i] = z4;

    // ---- phase 1: xe_t @ w_ih^T from prefetched fragments ----
    #pragma unroll
    for (int kt = 0; kt < 4; ++kt) {
      v8bf a0 = __builtin_bit_cast(v8bf, pf[kt * 2]);
      v8bf a1f = __builtin_bit_cast(v8bf, pf[kt * 2 + 1]);
      int ch = wv * 16 + kt * 4 + lq;
      int rR = l16, rZ = 16 + l16, rN = 32 + l16;
      v8bf bR = ldb8(wih_s + rR * E_ + ((ch ^ (rR & 7)) << 3));
      v8bf bZ = ldb8(wih_s + rZ * E_ + ((ch ^ (rZ & 7)) << 3));
      v8bf bN = ldb8(wih_s + rN * E_ + ((ch ^ (rN & 7)) << 3));
      acc[0] = MF(a0, bR, acc[0]); acc[1] = MF(a1f, bR, acc[1]);
      acc[2] = MF(a0, bZ, acc[2]); acc[3] = MF(a1f, bZ, acc[3]);
      acc[4] = MF(a0, bN, acc[4]); acc[5] = MF(a1f, bN, acc[5]);
    }
    // issue prefetch for t+1 (in flight across poll/phase2/reduction)
    {
      const USH* a1n = a1b + (t + 1 < T_ ? t + 1 : t) * E_;
      #pragma unroll
      for (int kt = 0; kt < 4; ++kt) {
        pf[kt * 2]     = *reinterpret_cast<const uint4*>(a1n + kt * 32);
        pf[kt * 2 + 1] = *reinterpret_cast<const uint4*>(a1n + 16 * (T_ * E_) + kt * 32);
      }
    }

    // ---- per-wave wait: ballot-poll the 16 producer flags of my K-chunk ----
    if (t > 0) {
      u32 tgt = (u32)t;
      while (true) {
        u32 f = __hip_atomic_load(wflag, __ATOMIC_RELAXED, __HIP_MEMORY_SCOPE_AGENT);
        if (__ballot(f >= tgt) == ~0ull) break;
        __builtin_amdgcn_s_sleep(2);
      }
      asm volatile("" ::: "memory");
    }

    // ---- phase 2: h_{t-1} @ w_hh^T (h via coherent relaxed-agent loads) ----
    const USH* a2 = a2b + ((t & 1) ^ 1) * (B_ * H_);
    #pragma unroll
    for (int kt = 0; kt < 8; ++kt) {
      v8bf a0 = ldh8(a2 + kt * 32);
      v8bf a1f = ldh8(a2 + 16 * H_ + kt * 32);
      int ch = wv * 32 + kt * 4 + lq;
      int rR = l16, rZ = 16 + l16, rN = 32 + l16;
      v8bf bR = ldb8(whh_s + rR * H_ + ((ch ^ (rR & 7)) << 3));
      v8bf bZ = ldb8(whh_s + rZ * H_ + ((ch ^ (rZ & 7)) << 3));
      v8bf bN = ldb8(whh_s + rN * H_ + ((ch ^ (rN & 7)) << 3));
      acc[0] = MF(a0, bR, acc[0]); acc[1] = MF(a1f, bR, acc[1]);
      acc[2] = MF(a0, bZ, acc[2]); acc[3] = MF(a1f, bZ, acc[3]);
      acc[6] = MF(a0, bN, acc[6]); acc[7] = MF(a1f, bN, acc[7]);
    }

    // ---- cross-wave reduction (two 12KB rounds) ----
    if (wv != 0) {
      #pragma unroll
      for (int f = 0; f < 4; ++f) rv[(wv - 1) * 256 + f * 64 + ln] = acc[f];
    }
    __syncthreads();
    if (wv == 0) {
      #pragma unroll
      for (int w = 0; w < 3; ++w) {
        #pragma unroll
        for (int f = 0; f < 4; ++f) acc[f] += rv[w * 256 + f * 64 + ln];
      }
    }
    __syncthreads();
    if (wv != 0) {
      #pragma unroll
      for (int f = 0; f < 4; ++f) rv[(wv - 1) * 256 + f * 64 + ln] = acc[4 + f];
    }
    __syncthreads();
    if (wv == 0) {
      #pragma unroll
      for (int w = 0; w < 3; ++w) {
        #pragma unroll
        for (int f = 0; f < 4; ++f) acc[4 + f] += rv[w * 256 + f * 64 + ln];
      }
      // ---- gates + state update (wave0 owns this block's (b,c) outputs) ----
      #pragma unroll
      for (int mm = 0; mm < 2; ++mm) {
        #pragma unroll
        for (int r4 = 0; r4 < 4; ++r4) {
          float rg = sigm(acc[0 + mm][r4] + bir + bhr);
          float zg = sigm(acc[2 + mm][r4] + biz + bhz);
          float ng = tanhx(acc[4 + mm][r4] + bin + rg * (acc[6 + mm][r4] + bhn));
          int hi = mm * 4 + r4;
          float hn = (1.f - zg) * ng + zg * hp[hi];
          hp[hi] = hn;
          tr[mm * 16 + lq * 4 + r4][l16] = f2b(hn);   // LDS transpose
        }
      }
      // read back one 16B row-segment per lane: row = ln>>1, half = ln&1
      {
        int row = ln >> 1, half = ln & 1;
        uint4 hv = *reinterpret_cast<const uint4*>(&tr[row][half * 8]);
        int b = b0 + row;
        USH* dsth = hg + (t & 1) * (B_ * H_) + b * H_ + c0 + half * 8;
        sth16(dsth, hv);                                           // coherent store for next step
        *reinterpret_cast<uint4*>(hs + (long)t * (B_ * H_) + b * H_ + c0 + half * 8) = hv;  // history
      }
      asm volatile("s_waitcnt vmcnt(0)" ::: "memory");  // h stores visible at coherence point
      if (ln == 0)
        __hip_atomic_store(myflag, (u32)(t + 1), __ATOMIC_RELAXED, __HIP_MEMORY_SCOPE_AGENT);
    }
  }
}

// ---------------- emissions: em[b,t,k] = hs[t,b,:] . fc_w[k,:] + fc_b[k] ----------------
__global__ __launch_bounds__(256) void emisk(const USH* __restrict__ hs, const USH* __restrict__ fcwB,
                                             const float* __restrict__ fcb, float* __restrict__ em) {
  __shared__ float red[3 * 256 * 4];
  int t = blockIdx.x >> 2, bq = blockIdx.x & 3;
  int tid = threadIdx.x, wv = tid >> 6, ln = tid & 63, l16 = ln & 15, lq = ln >> 4;
  int b0 = bq * 16;
  const USH* ab = hs + (t * 64 + b0 + l16) * H_ + wv * 256 + 8 * lq;
  const v4f z4 = {0.f, 0.f, 0.f, 0.f};
  v4f acc[4];
  #pragma unroll
  for (int i = 0; i < 4; ++i) acc[i] = z4;
  #pragma unroll
  for (int kt = 0; kt < 8; ++kt) {
    v8bf a = ldb8(ab + kt * 32);
    #pragma unroll
    for (int nt = 0; nt < 4; ++nt) {
      const USH* bp = fcwB + (nt * 16 + l16) * H_ + wv * 256 + kt * 32 + 8 * lq;
      acc[nt] = MF(a, ldb8(bp), acc[nt]);
    }
  }
  v4f* rv = reinterpret_cast<v4f*>(red);
  if (wv != 0) {
    #pragma unroll
    for (int nt = 0; nt < 4; ++nt) rv[(wv - 1) * 256 + nt * 64 + ln] = acc[nt];
  }
  __syncthreads();
  if (wv == 0) {
    #pragma unroll
    for (int nt = 0; nt < 4; ++nt) {
      v4f s = acc[nt];
      #pragma unroll
      for (int w = 0; w < 3; ++w) s += rv[w * 256 + nt * 64 + ln];
      int k = nt * 16 + l16;
      float bias = fcb[k];
      #pragma unroll
      for (int r = 0; r < 4; ++r) {
        int b = b0 + lq * 4 + r;
        em[(b * T_ + t) * 64 + k] = s[r] + bias;
      }
    }
  }
}

// ---------------- CRF NLL per batch element ----------------
__global__ __launch_bounds__(64) void crfk(const float* __restrict__ em, const int* __restrict__ tags,
                                           const float* __restrict__ st, const float* __restrict__ en,
                                           const float* __restrict__ tr, float* __restrict__ res) {
  int b = blockIdx.x, j = threadIdx.x;
  __shared__ float trs[4096];
  for (int i = j; i < 4096; i += 64) trs[i] = tr[i];
  __syncthreads();
  const int* tg = tags + b * T_;
  const float* e = em + (long)b * T_ * 64;
  // numerator (gold path score), t-parallel
  float np = 0.f;
  for (int t = j; t < T_; t += 64) {
    int ct = tg[t];
    np += e[t * 64 + ct];
    if (t > 0) np += trs[tg[t - 1] * 64 + ct];
  }
  #pragma unroll
  for (int o = 32; o; o >>= 1) np += __shfl_xor(np, o, 64);
  float num = np + st[tg[0]] + en[tg[T_ - 1]];
  // forward algorithm; lane j holds alpha[j]
  float alpha = st[j] + e[j];
  for (int t = 1; t < T_; ++t) {
    float m = -3.4e38f;
    #pragma unroll 8
    for (int i = 0; i < 64; ++i) {
      float v = __shfl(alpha, i, 64) + trs[i * 64 + j];
      m = fmaxf(m, v);
    }
    float s = 0.f;
    #pragma unroll 8
    for (int i = 0; i < 64; ++i) {
      float v = __shfl(alpha, i, 64) + trs[i * 64 + j];
      s += __expf(v - m);
    }
    alpha = m + __logf(s) + e[t * 64 + j];
  }
  float v = alpha + en[j];
  float mm = v;
  #pragma unroll
  for (int o = 32; o; o >>= 1) mm = fmaxf(mm, __shfl_xor(mm, o, 64));
  float ss = __expf(v - mm);
  #pragma unroll
  for (int o = 32; o; o >>= 1) ss += __shfl_xor(ss, o, 64);
  if (j == 0) res[b] = (mm + __logf(ss)) - num;
}

__global__ void fin(const float* __restrict__ res, float* __restrict__ out) {
  float v = res[threadIdx.x];
  #pragma unroll
  for (int o = 32; o; o >>= 1) v += __shfl_xor(v, o, 64);
  if (threadIdx.x == 0) out[0] = v;
}

extern "C" void kernel_launch(void* const* d_in, const int* in_sizes, int n_in,
                              void* d_out, int out_size, void* d_ws, size_t ws_size,
                              hipStream_t stream) {
  (void)in_sizes; (void)n_in; (void)out_size;
  const int*   x    = (const int*)d_in[0];
  const int*   tags = (const int*)d_in[1];
  const float* emb  = (const float*)d_in[2];
  const float* wih  = (const float*)d_in[3];
  const float* whh  = (const float*)d_in[4];
  const float* bih  = (const float*)d_in[5];
  const float* bhh  = (const float*)d_in[6];
  const float* fcw  = (const float*)d_in[7];
  const float* fcb  = (const float*)d_in[8];
  const float* str  = (const float*)d_in[9];
  const float* enr  = (const float*)d_in[10];
  const float* trn  = (const float*)d_in[11];

  char* ws = (char*)d_ws;
  // workspace layout (bytes) — same footprint as round 2
  USH*   xeb  = (USH*)(ws + 0);           // 33,554,432
  USH*   wihB = (USH*)(ws + 33554432);    //  3,145,728
  USH*   whhB = (USH*)(ws + 36700160);    //  6,291,456
  USH*   fcwB = (USH*)(ws + 42991616);    //    131,072
  USH*   hg   = (USH*)(ws + 43122688);    //    262,144 (2 x [64][1024] bf16)
  USH*   hs   = (USH*)(ws + 43385088);    // 67,108,864 ([T][B][H] bf16)
  float* em   = (float*)(ws + 110493952); //  8,388,608 ([B][T][64] f32)
  u32*   flags= (u32*)em;                 //  8,192 B: one 64B line per block; dead before emisk
  float* res  = (float*)(ws + 118882560); //        256
  if (ws_size < 118882816ull) return;

  // zero h double-buffer + flags (runs every call / every replay)
  hipMemsetAsync(hg, 0, 262144, stream);
  hipMemsetAsync(flags, 0, 8192, stream);

  castk<<<1536, 256, 0, stream>>>(wih, wihB, 3 * H_ * E_);
  castk<<<3072, 256, 0, stream>>>(whh, whhB, 3 * H_ * H_);
  castk<<<64, 256, 0, stream>>>(fcw, fcwB, 64 * H_);
  gatherk<<<B_ * T_, 128, 0, stream>>>(x, emb, xeb);
  gru_scan<<<128, 256, 0, stream>>>(xeb, wihB, whhB, bih, bhh, hg, flags, hs);
  emisk<<<T_ * 4, 256, 0, stream>>>(hs, fcwB, fcb, em);
  crfk<<<B_, 64, 0, stream>>>(em, tags, str, enr, trn, res);
  fin<<<1, 64, 0, stream>>>(res, (float*)d_out);
}

// Round 4
// 3314.112 us; speedup vs baseline: 3.2791x; 1.4359x over previous
//
#include <hip/hip_runtime.h>

typedef unsigned short USH;
typedef unsigned int u32;
typedef unsigned long long u64;
typedef float v4f __attribute__((ext_vector_type(4)));
typedef __bf16 v8bf __attribute__((ext_vector_type(8)));
typedef u32 v4u __attribute__((ext_vector_type(4)));

#define B_ 64
#define T_ 512
#define E_ 512
#define H_ 1024

__device__ __forceinline__ USH f2b(float x) {
  union { float f; u32 u; } v; v.f = x;
  u32 r = v.u + 0x7FFFu + ((v.u >> 16) & 1u);
  return (USH)(r >> 16);
}
__device__ __forceinline__ v8bf ldb8(const USH* p) {
  uint4 u = *reinterpret_cast<const uint4*>(p);
  return __builtin_bit_cast(v8bf, u);
}
__device__ __forceinline__ v4f MF(v8bf a, v8bf b, v4f c) {
  return __builtin_amdgcn_mfma_f32_16x16x32_bf16(a, b, c, 0, 0, 0);
}
__device__ __forceinline__ float sigm(float x) { return 1.0f / (1.0f + __expf(-x)); }
__device__ __forceinline__ float tanhx(float x) { return 1.0f - 2.0f / (__expf(2.0f * x) + 1.0f); }

// coherent (cross-XCD) 16B ops: sc0=bypass L1, sc1=bypass L2 (agent scope)
__device__ __forceinline__ v4u ldc16(u64 a) {
  v4u d;
  asm volatile("global_load_dwordx4 %0, %1, off sc0 sc1" : "=v"(d) : "v"(a));
  return d;
}
__device__ __forceinline__ void stc16(u64 a, v4u d) {
  asm volatile("global_store_dwordx4 %0, %1, off sc1" :: "v"(a), "v"(d) : "memory");
}

// ---------------- f32 -> bf16 cast ----------------
__global__ void castk(const float* __restrict__ s, USH* __restrict__ d, int n) {
  int i = (blockIdx.x * 256 + threadIdx.x) * 4;
  if (i >= n) return;
  float4 v = *reinterpret_cast<const float4*>(s + i);
  ushort4 q = make_ushort4(f2b(v.x), f2b(v.y), f2b(v.z), f2b(v.w));
  *reinterpret_cast<ushort4*>(d + i) = q;
}

// ---------------- embedding gather (-> bf16) ----------------
__global__ void gatherk(const int* __restrict__ x, const float* __restrict__ emb, USH* __restrict__ xeb) {
  int r = blockIdx.x;                       // r = b*T + t
  int id = x[r];
  const float4* e = reinterpret_cast<const float4*>(emb + (long)id * E_);
  float4 v = e[threadIdx.x];                // 128 threads * 4 floats = 512
  ushort4 q = make_ushort4(f2b(v.x), f2b(v.y), f2b(v.z), f2b(v.w));
  *reinterpret_cast<ushort4*>(xeb + (long)r * E_ + threadIdx.x * 4) = q;
}

// ---------------- persistent GRU scan ----------------
// grid = 128 blocks: bg = blk>>6 (batch group of 32 rows), cb = blk&63 (16 h-cols)
// h exchange: compact [cb][row32][col16] per (group,parity); producer = ONE dwordx4 sc1
// store; consumers = 16 coalesced dwordx4 sc0+sc1 loads. Flags packed 64x4B per group,
// polled by wave1 only; __syncthreads releases the block.
__global__ __launch_bounds__(256, 1) void gru_scan(
    const USH* __restrict__ xeb, const USH* __restrict__ wihB, const USH* __restrict__ whhB,
    const float* __restrict__ bih, const float* __restrict__ bhh,
    char* __restrict__ hg, u32* __restrict__ flags, USH* __restrict__ hs)
{
  __shared__ USH wih_s[48 * 512];     // 48KB
  __shared__ USH whh_s[48 * 1024];    // 96KB
  __shared__ float red[3 * 256 * 4];  // 12KB reduction buffer (reused as h-transpose)

  const int tid = threadIdx.x;
  const int wv = tid >> 6, ln = tid & 63;
  const int l16 = ln & 15, lq = ln >> 4;
  const int bg = blockIdx.x >> 6, cb = blockIdx.x & 63;
  const int b0 = bg * 32, c0 = cb * 16;

  // load weight slices into LDS, 16B-chunk XOR swizzle (chunk ^= row&7)
  for (int i = tid; i < 48 * 64; i += 256) {
    int row = i >> 6, ch = i & 63;
    int g = (row >> 4) * H_ + c0 + (row & 15);
    uint4 v = *reinterpret_cast<const uint4*>(wihB + g * E_ + ch * 8);
    *reinterpret_cast<uint4*>(wih_s + row * E_ + ((ch ^ (row & 7)) << 3)) = v;
  }
  for (int i = tid; i < 48 * 128; i += 256) {
    int row = i >> 7, ch = i & 127;
    int g = (row >> 4) * H_ + c0 + (row & 15);
    uint4 v = *reinterpret_cast<const uint4*>(whhB + g * H_ + ch * 8);
    *reinterpret_cast<uint4*>(whh_s + row * H_ + ((ch ^ (row & 7)) << 3)) = v;
  }
  __syncthreads();

  const int cgl = c0 + l16;
  const float bir = bih[cgl], biz = bih[H_ + cgl], bin = bih[2 * H_ + cgl];
  const float bhr = bhh[cgl], bhz = bhh[H_ + cgl], bhn = bhh[2 * H_ + cgl];

  const USH* a1b = xeb + (b0 + l16) * (T_ * E_) + wv * 128 + 8 * lq;
  // h buffers: hg + (bg*2 + parity)*65536; per-lane invariant offset for loads
  const u64 hrd0 = (u64)(uintptr_t)(hg + bg * 2 * 65536);
  const int lane_off = (wv * 16 + (lq >> 1)) * 1024 + l16 * 32 + (lq & 1) * 16;
  // flags: 64 u32 per group
  const u64 fl0 = (u64)(uintptr_t)(flags + bg * 64);
  const u64 myfl = fl0 + (u64)cb * 4;

  float hp[8];
  #pragma unroll
  for (int i = 0; i < 8; ++i) hp[i] = 0.f;

  v4f* rv = reinterpret_cast<v4f*>(red);
  USH* trp = reinterpret_cast<USH*>(red);     // 1KB transpose area (red reused)
  const v4f z4 = {0.f, 0.f, 0.f, 0.f};

  // prefetch xe A-fragments for t=0
  uint4 pf[8];
  #pragma unroll
  for (int kt = 0; kt < 4; ++kt) {
    pf[kt * 2]     = *reinterpret_cast<const uint4*>(a1b + kt * 32);
    pf[kt * 2 + 1] = *reinterpret_cast<const uint4*>(a1b + 16 * (T_ * E_) + kt * 32);
  }

  for (int t = 0; t < T_; ++t) {
    v4f acc[8];  // 0/1:R(m0,m1) 2/3:Z 4/5:NI 6/7:NH
    #pragma unroll
    for (int i = 0; i < 8; ++i) acc[i] = z4;

    // ---- phase 1: xe_t @ w_ih^T from prefetched fragments ----
    #pragma unroll
    for (int kt = 0; kt < 4; ++kt) {
      v8bf a0 = __builtin_bit_cast(v8bf, pf[kt * 2]);
      v8bf a1f = __builtin_bit_cast(v8bf, pf[kt * 2 + 1]);
      int ch = wv * 16 + kt * 4 + lq;
      int rR = l16, rZ = 16 + l16, rN = 32 + l16;
      v8bf bR = ldb8(wih_s + rR * E_ + ((ch ^ (rR & 7)) << 3));
      v8bf bZ = ldb8(wih_s + rZ * E_ + ((ch ^ (rZ & 7)) << 3));
      v8bf bN = ldb8(wih_s + rN * E_ + ((ch ^ (rN & 7)) << 3));
      acc[0] = MF(a0, bR, acc[0]); acc[1] = MF(a1f, bR, acc[1]);
      acc[2] = MF(a0, bZ, acc[2]); acc[3] = MF(a1f, bZ, acc[3]);
      acc[4] = MF(a0, bN, acc[4]); acc[5] = MF(a1f, bN, acc[5]);
    }

    // ---- wave1 polls all 64 producer flags (packed: 4 lines/poll) ----
    if (t > 0 && wv == 1) {
      u32 f;
      const u64 fa = fl0 + (u64)ln * 4;
      while (true) {
        asm volatile("global_load_dword %0, %1, off sc0 sc1\n\ts_waitcnt vmcnt(0)"
                     : "=v"(f) : "v"(fa) : "memory");
        if (__ballot((int)f >= t) == ~0ull) break;
        __builtin_amdgcn_s_sleep(1);
      }
    }
    __syncthreads();   // sync0: releases all waves once h_{t-1} globally visible

    // ---- phase 2: h_{t-1} @ w_hh^T; 16 coalesced coherent 16B loads ----
    {
      const u64 hb = hrd0 + (u64)(((t & 1) ^ 1) * 65536) + lane_off;
      v4u ha[16];
      #pragma unroll
      for (int kt = 0; kt < 8; ++kt) {
        #pragma unroll
        for (int mm = 0; mm < 2; ++mm)
          ha[kt * 2 + mm] = ldc16(hb + kt * 2048 + mm * 512);
      }
      asm volatile("s_waitcnt vmcnt(0)" ::: "memory");
      #pragma unroll
      for (int kt = 0; kt < 8; ++kt) {
        v8bf a0 = __builtin_bit_cast(v8bf, ha[kt * 2]);
        v8bf a1f = __builtin_bit_cast(v8bf, ha[kt * 2 + 1]);
        int ch = wv * 32 + kt * 4 + lq;
        int rR = l16, rZ = 16 + l16, rN = 32 + l16;
        v8bf bR = ldb8(whh_s + rR * H_ + ((ch ^ (rR & 7)) << 3));
        v8bf bZ = ldb8(whh_s + rZ * H_ + ((ch ^ (rZ & 7)) << 3));
        v8bf bN = ldb8(whh_s + rN * H_ + ((ch ^ (rN & 7)) << 3));
        acc[0] = MF(a0, bR, acc[0]); acc[1] = MF(a1f, bR, acc[1]);
        acc[2] = MF(a0, bZ, acc[2]); acc[3] = MF(a1f, bZ, acc[3]);
        acc[6] = MF(a0, bN, acc[6]); acc[7] = MF(a1f, bN, acc[7]);
      }
    }

    // ---- cross-wave reduction (two 12KB rounds) ----
    if (wv != 0) {
      #pragma unroll
      for (int f = 0; f < 4; ++f) rv[(wv - 1) * 256 + f * 64 + ln] = acc[f];
    }
    __syncthreads();
    if (wv == 0) {
      #pragma unroll
      for (int w = 0; w < 3; ++w) {
        #pragma unroll
        for (int f = 0; f < 4; ++f) acc[f] += rv[w * 256 + f * 64 + ln];
      }
    }
    __syncthreads();
    if (wv != 0) {
      #pragma unroll
      for (int f = 0; f < 4; ++f) rv[(wv - 1) * 256 + f * 64 + ln] = acc[4 + f];
    }
    __syncthreads();
    if (wv == 0) {
      #pragma unroll
      for (int w = 0; w < 3; ++w) {
        #pragma unroll
        for (int f = 0; f < 4; ++f) acc[4 + f] += rv[w * 256 + f * 64 + ln];
      }
      // ---- gates + state update; transpose via red-reuse LDS ----
      #pragma unroll
      for (int mm = 0; mm < 2; ++mm) {
        #pragma unroll
        for (int r4 = 0; r4 < 4; ++r4) {
          float rg = sigm(acc[0 + mm][r4] + bir + bhr);
          float zg = sigm(acc[2 + mm][r4] + biz + bhz);
          float ng = tanhx(acc[4 + mm][r4] + bin + rg * (acc[6 + mm][r4] + bhn));
          int hi = mm * 4 + r4;
          float hn = (1.f - zg) * ng + zg * hp[hi];
          hp[hi] = hn;
          trp[(mm * 16 + lq * 4 + r4) * 16 + l16] = f2b(hn);
        }
      }
      // one 16B segment per lane: row = ln>>1, half = ln&1 (contiguous 1KB block)
      v4u hv = *reinterpret_cast<const v4u*>(trp + ln * 8);
      u64 pa = hrd0 + (u64)((t & 1) * 65536) + (u64)cb * 1024 + (u64)ln * 16;
      stc16(pa, hv);
      asm volatile("s_waitcnt vmcnt(0)" ::: "memory");   // only the h-store outstanding
      if (ln == 0) {
        u32 val = (u32)(t + 1);
        asm volatile("global_store_dword %0, %1, off sc1" :: "v"(myfl), "v"(val) : "memory");
      }
      // off-critical-path: history store (plain, L2-cached)
      *reinterpret_cast<v4u*>(hs + (long)t * (B_ * H_) + (b0 + (ln >> 1)) * H_ + c0 + (ln & 1) * 8) = hv;
    }

    // ---- xe prefetch for t+1 (issued after release; hides under next poll) ----
    {
      const USH* a1n = a1b + (t + 1 < T_ ? t + 1 : t) * E_;
      #pragma unroll
      for (int kt = 0; kt < 4; ++kt) {
        pf[kt * 2]     = *reinterpret_cast<const uint4*>(a1n + kt * 32);
        pf[kt * 2 + 1] = *reinterpret_cast<const uint4*>(a1n + 16 * (T_ * E_) + kt * 32);
      }
    }
  }
}

// ---------------- emissions: em[b,t,k] = hs[t,b,:] . fc_w[k,:] + fc_b[k] ----------------
__global__ __launch_bounds__(256) void emisk(const USH* __restrict__ hs, const USH* __restrict__ fcwB,
                                             const float* __restrict__ fcb, float* __restrict__ em) {
  __shared__ float red[3 * 256 * 4];
  int t = blockIdx.x >> 2, bq = blockIdx.x & 3;
  int tid = threadIdx.x, wv = tid >> 6, ln = tid & 63, l16 = ln & 15, lq = ln >> 4;
  int b0 = bq * 16;
  const USH* ab = hs + (t * 64 + b0 + l16) * H_ + wv * 256 + 8 * lq;
  const v4f z4 = {0.f, 0.f, 0.f, 0.f};
  v4f acc[4];
  #pragma unroll
  for (int i = 0; i < 4; ++i) acc[i] = z4;
  #pragma unroll
  for (int kt = 0; kt < 8; ++kt) {
    v8bf a = ldb8(ab + kt * 32);
    #pragma unroll
    for (int nt = 0; nt < 4; ++nt) {
      const USH* bp = fcwB + (nt * 16 + l16) * H_ + wv * 256 + kt * 32 + 8 * lq;
      acc[nt] = MF(a, ldb8(bp), acc[nt]);
    }
  }
  v4f* rv = reinterpret_cast<v4f*>(red);
  if (wv != 0) {
    #pragma unroll
    for (int nt = 0; nt < 4; ++nt) rv[(wv - 1) * 256 + nt * 64 + ln] = acc[nt];
  }
  __syncthreads();
  if (wv == 0) {
    #pragma unroll
    for (int nt = 0; nt < 4; ++nt) {
      v4f s = acc[nt];
      #pragma unroll
      for (int w = 0; w < 3; ++w) s += rv[w * 256 + nt * 64 + ln];
      int k = nt * 16 + l16;
      float bias = fcb[k];
      #pragma unroll
      for (int r = 0; r < 4; ++r) {
        int b = b0 + lq * 4 + r;
        em[(b * T_ + t) * 64 + k] = s[r] + bias;
      }
    }
  }
}

// ---------------- CRF NLL per batch element ----------------
__global__ __launch_bounds__(64) void crfk(const float* __restrict__ em, const int* __restrict__ tags,
                                           const float* __restrict__ st, const float* __restrict__ en,
                                           const float* __restrict__ tr, float* __restrict__ res) {
  int b = blockIdx.x, j = threadIdx.x;
  __shared__ float trs[4096];
  for (int i = j; i < 4096; i += 64) trs[i] = tr[i];
  __syncthreads();
  const int* tg = tags + b * T_;
  const float* e = em + (long)b * T_ * 64;
  // numerator (gold path score), t-parallel
  float np = 0.f;
  for (int t = j; t < T_; t += 64) {
    int ct = tg[t];
    np += e[t * 64 + ct];
    if (t > 0) np += trs[tg[t - 1] * 64 + ct];
  }
  #pragma unroll
  for (int o = 32; o; o >>= 1) np += __shfl_xor(np, o, 64);
  float num = np + st[tg[0]] + en[tg[T_ - 1]];
  // forward algorithm; lane j holds alpha[j]; vv cached in regs, 4 indep chains
  float alpha = st[j] + e[j];
  for (int t = 1; t < T_; ++t) {
    float vv[64];
    #pragma unroll
    for (int i = 0; i < 64; ++i) vv[i] = __shfl(alpha, i, 64) + trs[i * 64 + j];
    float mc[4];
    #pragma unroll
    for (int c = 0; c < 4; ++c) {
      mc[c] = vv[c * 16];
      #pragma unroll
      for (int ii = 1; ii < 16; ++ii) mc[c] = fmaxf(mc[c], vv[c * 16 + ii]);
    }
    float M = fmaxf(fmaxf(mc[0], mc[1]), fmaxf(mc[2], mc[3]));
    float sc[4] = {0.f, 0.f, 0.f, 0.f};
    #pragma unroll
    for (int c = 0; c < 4; ++c)
      #pragma unroll
      for (int ii = 0; ii < 16; ++ii) sc[c] += __expf(vv[c * 16 + ii] - M);
    alpha = M + __logf((sc[0] + sc[1]) + (sc[2] + sc[3])) + e[t * 64 + j];
  }
  float v = alpha + en[j];
  float mm = v;
  #pragma unroll
  for (int o = 32; o; o >>= 1) mm = fmaxf(mm, __shfl_xor(mm, o, 64));
  float ss = __expf(v - mm);
  #pragma unroll
  for (int o = 32; o; o >>= 1) ss += __shfl_xor(ss, o, 64);
  if (j == 0) res[b] = (mm + __logf(ss)) - num;
}

__global__ void fin(const float* __restrict__ res, float* __restrict__ out) {
  float v = res[threadIdx.x];
  #pragma unroll
  for (int o = 32; o; o >>= 1) v += __shfl_xor(v, o, 64);
  if (threadIdx.x == 0) out[0] = v;
}

extern "C" void kernel_launch(void* const* d_in, const int* in_sizes, int n_in,
                              void* d_out, int out_size, void* d_ws, size_t ws_size,
                              hipStream_t stream) {
  (void)in_sizes; (void)n_in; (void)out_size;
  const int*   x    = (const int*)d_in[0];
  const int*   tags = (const int*)d_in[1];
  const float* emb  = (const float*)d_in[2];
  const float* wih  = (const float*)d_in[3];
  const float* whh  = (const float*)d_in[4];
  const float* bih  = (const float*)d_in[5];
  const float* bhh  = (const float*)d_in[6];
  const float* fcw  = (const float*)d_in[7];
  const float* fcb  = (const float*)d_in[8];
  const float* str  = (const float*)d_in[9];
  const float* enr  = (const float*)d_in[10];
  const float* trn  = (const float*)d_in[11];

  char* ws = (char*)d_ws;
  // workspace layout (bytes)
  USH*   xeb  = (USH*)(ws + 0);           // 33,554,432
  USH*   wihB = (USH*)(ws + 33554432);    //  3,145,728
  USH*   whhB = (USH*)(ws + 36700160);    //  6,291,456
  USH*   fcwB = (USH*)(ws + 42991616);    //    131,072
  char*  hg   = (char*)(ws + 43122688);   //    262,144 (4 x 64KB: [group][parity][cb][row][col])
  USH*   hs   = (USH*)(ws + 43385088);    // 67,108,864 ([T][B][H] bf16)
  float* em   = (float*)(ws + 110493952); //  8,388,608 ([B][T][64] f32)
  u32*   flags= (u32*)em;                 //    512 B: 2 groups x 64 packed flags; dead before emisk
  float* res  = (float*)(ws + 118882560); //        256
  if (ws_size < 118882816ull) return;

  // zero h buffers + flags (runs every call / every replay)
  hipMemsetAsync(hg, 0, 262144, stream);
  hipMemsetAsync(flags, 0, 512, stream);

  castk<<<1536, 256, 0, stream>>>(wih, wihB, 3 * H_ * E_);
  castk<<<3072, 256, 0, stream>>>(whh, whhB, 3 * H_ * H_);
  castk<<<64, 256, 0, stream>>>(fcw, fcwB, 64 * H_);
  gatherk<<<B_ * T_, 128, 0, stream>>>(x, emb, xeb);
  gru_scan<<<128, 256, 0, stream>>>(xeb, wihB, whhB, bih, bhh, hg, flags, hs);
  emisk<<<T_ * 4, 256, 0, stream>>>(hs, fcwB, fcb, em);
  crfk<<<B_, 64, 0, stream>>>(em, tags, str, enr, trn, res);
  fin<<<1, 64, 0, stream>>>(res, (float*)d_out);
}

// Round 5
// 3200.915 us; speedup vs baseline: 3.3951x; 1.0354x over previous
//
#include <hip/hip_runtime.h>

typedef unsigned short USH;
typedef unsigned int u32;
typedef unsigned long long u64;
typedef float v4f __attribute__((ext_vector_type(4)));
typedef __bf16 v8bf __attribute__((ext_vector_type(8)));
typedef u32 v4u __attribute__((ext_vector_type(4)));

#define B_ 64
#define T_ 512
#define E_ 512
#define H_ 1024

__device__ __forceinline__ USH f2b(float x) {
  union { float f; u32 u; } v; v.f = x;
  u32 r = v.u + 0x7FFFu + ((v.u >> 16) & 1u);
  return (USH)(r >> 16);
}
__device__ __forceinline__ v8bf ldb8(const USH* p) {
  uint4 u = *reinterpret_cast<const uint4*>(p);
  return __builtin_bit_cast(v8bf, u);
}
__device__ __forceinline__ v4f MF(v8bf a, v8bf b, v4f c) {
  return __builtin_amdgcn_mfma_f32_16x16x32_bf16(a, b, c, 0, 0, 0);
}
__device__ __forceinline__ float sigm(float x) { return 1.0f / (1.0f + __expf(-x)); }
__device__ __forceinline__ float tanhx(float x) { return 1.0f - 2.0f / (__expf(2.0f * x) + 1.0f); }

// coherent (cross-XCD) 16B ops: sc0=bypass L1, sc1=bypass L2 (to/from L3 coherence point)
__device__ __forceinline__ v4u ldc16(u64 a) {
  v4u d;
  asm volatile("global_load_dwordx4 %0, %1, off sc0 sc1" : "=v"(d) : "v"(a));
  return d;
}
__device__ __forceinline__ void stc16(u64 a, v4u d) {
  asm volatile("global_store_dwordx4 %0, %1, off sc1" :: "v"(a), "v"(d) : "memory");
}

// ---------------- f32 -> bf16 cast ----------------
__global__ void castk(const float* __restrict__ s, USH* __restrict__ d, int n) {
  int i = (blockIdx.x * 256 + threadIdx.x) * 4;
  if (i >= n) return;
  float4 v = *reinterpret_cast<const float4*>(s + i);
  ushort4 q = make_ushort4(f2b(v.x), f2b(v.y), f2b(v.z), f2b(v.w));
  *reinterpret_cast<ushort4*>(d + i) = q;
}

// ---------------- embedding gather (-> bf16) ----------------
__global__ void gatherk(const int* __restrict__ x, const float* __restrict__ emb, USH* __restrict__ xeb) {
  int r = blockIdx.x;                       // r = b*T + t
  int id = x[r];
  const float4* e = reinterpret_cast<const float4*>(emb + (long)id * E_);
  float4 v = e[threadIdx.x];                // 128 threads * 4 floats = 512
  ushort4 q = make_ushort4(f2b(v.x), f2b(v.y), f2b(v.z), f2b(v.w));
  *reinterpret_cast<ushort4*>(xeb + (long)r * E_ + threadIdx.x * 4) = q;
}

// ---------------- persistent GRU scan ----------------
// grid = 128 blocks: bg = blk>>6 (batch group of 32 rows), cb = blk&63 (16 h-cols).
// h exchange: per-STEP compact buffer hsC[t][bg][cb][ln] (sentinel 0xFF before launch).
// The DATA is the flag: consumers poll-load their 16 producer tiles and retry while
// any dword is 0xFFFFFFFF (bf16 h in [-1,1] never encodes 0xFFFF). Single L3 hop.
__global__ __launch_bounds__(256, 1) void gru_scan(
    const USH* __restrict__ xeb, const USH* __restrict__ wihB, const USH* __restrict__ whhB,
    const float* __restrict__ bih, const float* __restrict__ bhh,
    char* __restrict__ hsC)
{
  __shared__ USH wih_s[48 * 512];     // 48KB
  __shared__ USH whh_s[48 * 1024];    // 96KB
  __shared__ float red[3 * 256 * 4];  // 12KB reduction buffer (reused as h-transpose)

  const int tid = threadIdx.x;
  const int wv = tid >> 6, ln = tid & 63;
  const int l16 = ln & 15, lq = ln >> 4;
  const int bg = blockIdx.x >> 6, cb = blockIdx.x & 63;
  const int b0 = bg * 32, c0 = cb * 16;

  // load weight slices into LDS, 16B-chunk XOR swizzle (chunk ^= row&7)
  for (int i = tid; i < 48 * 64; i += 256) {
    int row = i >> 6, ch = i & 63;
    int g = (row >> 4) * H_ + c0 + (row & 15);
    uint4 v = *reinterpret_cast<const uint4*>(wihB + g * E_ + ch * 8);
    *reinterpret_cast<uint4*>(wih_s + row * E_ + ((ch ^ (row & 7)) << 3)) = v;
  }
  for (int i = tid; i < 48 * 128; i += 256) {
    int row = i >> 7, ch = i & 127;
    int g = (row >> 4) * H_ + c0 + (row & 15);
    uint4 v = *reinterpret_cast<const uint4*>(whhB + g * H_ + ch * 8);
    *reinterpret_cast<uint4*>(whh_s + row * H_ + ((ch ^ (row & 7)) << 3)) = v;
  }
  __syncthreads();

  const int cgl = c0 + l16;
  const float bir = bih[cgl], biz = bih[H_ + cgl], bin = bih[2 * H_ + cgl];
  const float bhr = bhh[cgl], bhz = bhh[H_ + cgl], bhn = bhh[2 * H_ + cgl];

  const USH* a1b = xeb + (b0 + l16) * (T_ * E_) + wv * 128 + 8 * lq;
  // per-group base of the h stream; per-lane invariant consumer offset
  const u64 hC = (u64)(uintptr_t)(hsC) + (u64)bg * 65536;
  const int lane_off = (wv * 16 + (lq >> 1)) * 1024 + l16 * 32 + (lq & 1) * 16;

  float hp[8];
  #pragma unroll
  for (int i = 0; i < 8; ++i) hp[i] = 0.f;

  v4f* rv = reinterpret_cast<v4f*>(red);
  USH* trp = reinterpret_cast<USH*>(red);     // 1KB transpose area (red reused; safe: see poll ordering)
  const v4f z4 = {0.f, 0.f, 0.f, 0.f};

  // prefetch xe A-fragments for t=0
  uint4 pf[8];
  #pragma unroll
  for (int kt = 0; kt < 4; ++kt) {
    pf[kt * 2]     = *reinterpret_cast<const uint4*>(a1b + kt * 32);
    pf[kt * 2 + 1] = *reinterpret_cast<const uint4*>(a1b + 16 * (T_ * E_) + kt * 32);
  }

  for (int t = 0; t < T_; ++t) {
    v4f acc[8];  // 0/1:R(m0,m1) 2/3:Z 4/5:NI 6/7:NH
    #pragma unroll
    for (int i = 0; i < 8; ++i) acc[i] = z4;

    // ---- phase 1: xe_t @ w_ih^T from prefetched fragments ----
    #pragma unroll
    for (int kt = 0; kt < 4; ++kt) {
      v8bf a0 = __builtin_bit_cast(v8bf, pf[kt * 2]);
      v8bf a1f = __builtin_bit_cast(v8bf, pf[kt * 2 + 1]);
      int ch = wv * 16 + kt * 4 + lq;
      int rR = l16, rZ = 16 + l16, rN = 32 + l16;
      v8bf bR = ldb8(wih_s + rR * E_ + ((ch ^ (rR & 7)) << 3));
      v8bf bZ = ldb8(wih_s + rZ * E_ + ((ch ^ (rZ & 7)) << 3));
      v8bf bN = ldb8(wih_s + rN * E_ + ((ch ^ (rN & 7)) << 3));
      acc[0] = MF(a0, bR, acc[0]); acc[1] = MF(a1f, bR, acc[1]);
      acc[2] = MF(a0, bZ, acc[2]); acc[3] = MF(a1f, bZ, acc[3]);
      acc[4] = MF(a0, bN, acc[4]); acc[5] = MF(a1f, bN, acc[5]);
    }

    // ---- phase 2: poll-load h_{t-1} (data IS the flag), then h @ w_hh^T ----
    if (t > 0) {
      const u64 hb = hC + (u64)(t - 1) * 131072 + lane_off;
      v4u ha[16];
      while (true) {
        #pragma unroll
        for (int kt = 0; kt < 8; ++kt) {
          #pragma unroll
          for (int mm = 0; mm < 2; ++mm)
            ha[kt * 2 + mm] = ldc16(hb + kt * 2048 + mm * 512);
        }
        asm volatile("s_waitcnt vmcnt(0)" ::: "memory");
        bool bad = false;
        #pragma unroll
        for (int f = 0; f < 16; ++f) {
          #pragma unroll
          for (int d = 0; d < 4; ++d) bad |= (ha[f][d] == 0xFFFFFFFFu);
        }
        if (__ballot(bad) == 0ull) break;
        __builtin_amdgcn_s_sleep(1);
      }
      #pragma unroll
      for (int kt = 0; kt < 8; ++kt) {
        v8bf a0 = __builtin_bit_cast(v8bf, ha[kt * 2]);
        v8bf a1f = __builtin_bit_cast(v8bf, ha[kt * 2 + 1]);
        int ch = wv * 32 + kt * 4 + lq;
        int rR = l16, rZ = 16 + l16, rN = 32 + l16;
        v8bf bR = ldb8(whh_s + rR * H_ + ((ch ^ (rR & 7)) << 3));
        v8bf bZ = ldb8(whh_s + rZ * H_ + ((ch ^ (rZ & 7)) << 3));
        v8bf bN = ldb8(whh_s + rN * H_ + ((ch ^ (rN & 7)) << 3));
        acc[0] = MF(a0, bR, acc[0]); acc[1] = MF(a1f, bR, acc[1]);
        acc[2] = MF(a0, bZ, acc[2]); acc[3] = MF(a1f, bZ, acc[3]);
        acc[6] = MF(a0, bN, acc[6]); acc[7] = MF(a1f, bN, acc[7]);
      }
    }

    // ---- cross-wave reduction (two 12KB rounds) ----
    if (wv != 0) {
      #pragma unroll
      for (int f = 0; f < 4; ++f) rv[(wv - 1) * 256 + f * 64 + ln] = acc[f];
    }
    __syncthreads();
    if (wv == 0) {
      #pragma unroll
      for (int w = 0; w < 3; ++w) {
        #pragma unroll
        for (int f = 0; f < 4; ++f) acc[f] += rv[w * 256 + f * 64 + ln];
      }
    }
    __syncthreads();
    if (wv != 0) {
      #pragma unroll
      for (int f = 0; f < 4; ++f) rv[(wv - 1) * 256 + f * 64 + ln] = acc[4 + f];
    }
    __syncthreads();
    if (wv == 0) {
      #pragma unroll
      for (int w = 0; w < 3; ++w) {
        #pragma unroll
        for (int f = 0; f < 4; ++f) acc[4 + f] += rv[w * 256 + f * 64 + ln];
      }
      // ---- gates + state update; transpose via red-reuse LDS ----
      // safe: waves1-3 can't overwrite red until their NEXT-step poll succeeds,
      // which requires the stc16 below to have landed (after our trp read-back).
      #pragma unroll
      for (int mm = 0; mm < 2; ++mm) {
        #pragma unroll
        for (int r4 = 0; r4 < 4; ++r4) {
          float rg = sigm(acc[0 + mm][r4] + bir + bhr);
          float zg = sigm(acc[2 + mm][r4] + biz + bhz);
          float ng = tanhx(acc[4 + mm][r4] + bin + rg * (acc[6 + mm][r4] + bhn));
          int hi = mm * 4 + r4;
          float hn = (1.f - zg) * ng + zg * hp[hi];
          hp[hi] = hn;
          trp[(mm * 16 + lq * 4 + r4) * 16 + l16] = f2b(hn);
        }
      }
      // one 16B segment per lane into the per-step compact buffer; no ack, no flag
      v4u hv = *reinterpret_cast<const v4u*>(trp + ln * 8);
      stc16(hC + (u64)t * 131072 + (u64)cb * 1024 + (u64)ln * 16, hv);
    }

    // ---- xe prefetch for t+1 (hides under next step's poll) ----
    {
      const USH* a1n = a1b + (t + 1 < T_ ? t + 1 : t) * E_;
      #pragma unroll
      for (int kt = 0; kt < 4; ++kt) {
        pf[kt * 2]     = *reinterpret_cast<const uint4*>(a1n + kt * 32);
        pf[kt * 2 + 1] = *reinterpret_cast<const uint4*>(a1n + 16 * (T_ * E_) + kt * 32);
      }
    }
  }
}

// ---------------- emissions from compact h stream ----------------
// em[b,t,k] = hsC[t, b, :] . fc_w[k,:] + fc_b[k]
__global__ __launch_bounds__(256) void emisk(const char* __restrict__ hsC, const USH* __restrict__ fcwB,
                                             const float* __restrict__ fcb, float* __restrict__ em) {
  __shared__ float red[3 * 256 * 4];
  int t = blockIdx.x >> 2, bq = blockIdx.x & 3;
  int tid = threadIdx.x, wv = tid >> 6, ln = tid & 63, l16 = ln & 15, lq = ln >> 4;
  int b0 = bq * 16;
  // compact layout: addr = t*131072 + (b>>5)*65536 + (k>>4)*1024 + (b&31)*32 + (k&15)*2
  const u64 ab = (u64)(uintptr_t)hsC + (u64)t * 131072 + (u64)(bq >> 1) * 65536
               + (u64)((bq & 1) * 16 + l16) * 32 + (u64)(wv * 16 + (lq >> 1)) * 1024 + (u64)(lq & 1) * 16;
  const v4f z4 = {0.f, 0.f, 0.f, 0.f};
  v4f acc[4];
  #pragma unroll
  for (int i = 0; i < 4; ++i) acc[i] = z4;
  #pragma unroll
  for (int kt = 0; kt < 8; ++kt) {
    v4u u = ldc16(ab + kt * 2048);            // coherent: hsC was written with sc1
    asm volatile("s_waitcnt vmcnt(0)" ::: "memory");
    v8bf a = __builtin_bit_cast(v8bf, u);
    #pragma unroll
    for (int nt = 0; nt < 4; ++nt) {
      const USH* bp = fcwB + (nt * 16 + l16) * H_ + wv * 256 + kt * 32 + 8 * lq;
      acc[nt] = MF(a, ldb8(bp), acc[nt]);
    }
  }
  v4f* rv = reinterpret_cast<v4f*>(red);
  if (wv != 0) {
    #pragma unroll
    for (int nt = 0; nt < 4; ++nt) rv[(wv - 1) * 256 + nt * 64 + ln] = acc[nt];
  }
  __syncthreads();
  if (wv == 0) {
    #pragma unroll
    for (int nt = 0; nt < 4; ++nt) {
      v4f s = acc[nt];
      #pragma unroll
      for (int w = 0; w < 3; ++w) s += rv[w * 256 + nt * 64 + ln];
      int k = nt * 16 + l16;
      float bias = fcb[k];
      #pragma unroll
      for (int r = 0; r < 4; ++r) {
        int b = b0 + lq * 4 + r;
        em[(b * T_ + t) * 64 + k] = s[r] + bias;
      }
    }
  }
}

// ---------------- CRF NLL per batch element ----------------
__global__ __launch_bounds__(64) void crfk(const float* __restrict__ em, const int* __restrict__ tags,
                                           const float* __restrict__ st, const float* __restrict__ en,
                                           const float* __restrict__ tr, float* __restrict__ res) {
  int b = blockIdx.x, j = threadIdx.x;
  __shared__ float trs[4096];
  for (int i = j; i < 4096; i += 64) trs[i] = tr[i];
  __syncthreads();
  const int* tg = tags + b * T_;
  const float* e = em + (long)b * T_ * 64;
  // numerator (gold path score), t-parallel
  float np = 0.f;
  for (int t = j; t < T_; t += 64) {
    int ct = tg[t];
    np += e[t * 64 + ct];
    if (t > 0) np += trs[tg[t - 1] * 64 + ct];
  }
  #pragma unroll
  for (int o = 32; o; o >>= 1) np += __shfl_xor(np, o, 64);
  float num = np + st[tg[0]] + en[tg[T_ - 1]];
  // forward algorithm; lane j holds alpha[j]; vv cached in regs, 4 indep chains
  float alpha = st[j] + e[j];
  for (int t = 1; t < T_; ++t) {
    float vv[64];
    #pragma unroll
    for (int i = 0; i < 64; ++i) vv[i] = __shfl(alpha, i, 64) + trs[i * 64 + j];
    float mc[4];
    #pragma unroll
    for (int c = 0; c < 4; ++c) {
      mc[c] = vv[c * 16];
      #pragma unroll
      for (int ii = 1; ii < 16; ++ii) mc[c] = fmaxf(mc[c], vv[c * 16 + ii]);
    }
    float M = fmaxf(fmaxf(mc[0], mc[1]), fmaxf(mc[2], mc[3]));
    float sc[4] = {0.f, 0.f, 0.f, 0.f};
    #pragma unroll
    for (int c = 0; c < 4; ++c)
      #pragma unroll
      for (int ii = 0; ii < 16; ++ii) sc[c] += __expf(vv[c * 16 + ii] - M);
    alpha = M + __logf((sc[0] + sc[1]) + (sc[2] + sc[3])) + e[t * 64 + j];
  }
  float v = alpha + en[j];
  float mm = v;
  #pragma unroll
  for (int o = 32; o; o >>= 1) mm = fmaxf(mm, __shfl_xor(mm, o, 64));
  float ss = __expf(v - mm);
  #pragma unroll
  for (int o = 32; o; o >>= 1) ss += __shfl_xor(ss, o, 64);
  if (j == 0) res[b] = (mm + __logf(ss)) - num;
}

__global__ void fin(const float* __restrict__ res, float* __restrict__ out) {
  float v = res[threadIdx.x];
  #pragma unroll
  for (int o = 32; o; o >>= 1) v += __shfl_xor(v, o, 64);
  if (threadIdx.x == 0) out[0] = v;
}

extern "C" void kernel_launch(void* const* d_in, const int* in_sizes, int n_in,
                              void* d_out, int out_size, void* d_ws, size_t ws_size,
                              hipStream_t stream) {
  (void)in_sizes; (void)n_in; (void)out_size;
  const int*   x    = (const int*)d_in[0];
  const int*   tags = (const int*)d_in[1];
  const float* emb  = (const float*)d_in[2];
  const float* wih  = (const float*)d_in[3];
  const float* whh  = (const float*)d_in[4];
  const float* bih  = (const float*)d_in[5];
  const float* bhh  = (const float*)d_in[6];
  const float* fcw  = (const float*)d_in[7];
  const float* fcb  = (const float*)d_in[8];
  const float* str  = (const float*)d_in[9];
  const float* enr  = (const float*)d_in[10];
  const float* trn  = (const float*)d_in[11];

  char* ws = (char*)d_ws;
  // workspace layout (bytes)
  USH*   xeb  = (USH*)(ws + 0);           // 33,554,432
  USH*   wihB = (USH*)(ws + 33554432);    //  3,145,728
  USH*   whhB = (USH*)(ws + 36700160);    //  6,291,456
  USH*   fcwB = (USH*)(ws + 42991616);    //    131,072
  char*  hsC  = (char*)(ws + 43122688);   // 67,108,864: [t][group][cb][row][col] compact h stream
  float* em   = (float*)(ws + 110231552); //  8,388,608 ([B][T][64] f32)
  float* res  = (float*)(ws + 118620160); //        256
  if (ws_size < 118620416ull) return;

  // sentinel-fill the h stream (data-is-the-flag); runs every call / every replay
  hipMemsetAsync(hsC, 0xFF, 67108864, stream);

  castk<<<1536, 256, 0, stream>>>(wih, wihB, 3 * H_ * E_);
  castk<<<3072, 256, 0, stream>>>(whh, whhB, 3 * H_ * H_);
  castk<<<64, 256, 0, stream>>>(fcw, fcwB, 64 * H_);
  gatherk<<<B_ * T_, 128, 0, stream>>>(x, emb, xeb);
  gru_scan<<<128, 256, 0, stream>>>(xeb, wihB, whhB, bih, bhh, hsC);
  emisk<<<T_ * 4, 256, 0, stream>>>(hsC, fcwB, fcb, em);
  crfk<<<B_, 64, 0, stream>>>(em, tags, str, enr, trn, res);
  fin<<<1, 64, 0, stream>>>(res, (float*)d_out);
}

// Round 6
// 2685.191 us; speedup vs baseline: 4.0472x; 1.1921x over previous
//
#include <hip/hip_runtime.h>

typedef unsigned short USH;
typedef unsigned int u32;
typedef unsigned long long u64;
typedef float v4f __attribute__((ext_vector_type(4)));
typedef __bf16 v8bf __attribute__((ext_vector_type(8)));
typedef u32 v4u __attribute__((ext_vector_type(4)));

#define B_ 64
#define T_ 512
#define E_ 512
#define H_ 1024
#define NSCAN 128

__device__ __forceinline__ USH f2b(float x) {
  union { float f; u32 u; } v; v.f = x;
  u32 r = v.u + 0x7FFFu + ((v.u >> 16) & 1u);
  return (USH)(r >> 16);
}
__device__ __forceinline__ v8bf ldb8(const USH* p) {
  uint4 u = *reinterpret_cast<const uint4*>(p);
  return __builtin_bit_cast(v8bf, u);
}
__device__ __forceinline__ v4f MF(v8bf a, v8bf b, v4f c) {
  return __builtin_amdgcn_mfma_f32_16x16x32_bf16(a, b, c, 0, 0, 0);
}
__device__ __forceinline__ float sigm(float x) { return 1.0f / (1.0f + __expf(-x)); }
__device__ __forceinline__ float tanhx(float x) { return 1.0f - 2.0f / (__expf(2.0f * x) + 1.0f); }

// coherent (cross-XCD) ops: sc0=bypass L1, sc1=bypass L2
__device__ __forceinline__ v4u ldc16(u64 a) {
  v4u d;
  asm volatile("global_load_dwordx4 %0, %1, off sc0 sc1" : "=v"(d) : "v"(a));
  return d;
}
__device__ __forceinline__ void stc16(u64 a, v4u d) {
  asm volatile("global_store_dwordx4 %0, %1, off sc1" :: "v"(a), "v"(d) : "memory");
}

// ---------------- f32 -> bf16 cast ----------------
__global__ void castk(const float* __restrict__ s, USH* __restrict__ d, int n) {
  int i = (blockIdx.x * 256 + threadIdx.x) * 4;
  if (i >= n) return;
  float4 v = *reinterpret_cast<const float4*>(s + i);
  ushort4 q = make_ushort4(f2b(v.x), f2b(v.y), f2b(v.z), f2b(v.w));
  *reinterpret_cast<ushort4*>(d + i) = q;
}

// ---------------- embedding gather (-> bf16) ----------------
__global__ void gatherk(const int* __restrict__ x, const float* __restrict__ emb, USH* __restrict__ xeb) {
  int r = blockIdx.x;                       // r = b*T + t
  int id = x[r];
  const float4* e = reinterpret_cast<const float4*>(emb + (long)id * E_);
  float4 v = e[threadIdx.x];                // 128 threads * 4 floats = 512
  ushort4 q = make_ushort4(f2b(v.x), f2b(v.y), f2b(v.z), f2b(v.w));
  *reinterpret_cast<ushort4*>(xeb + (long)r * E_ + threadIdx.x * 4) = q;
}

// ---------------- fused persistent kernel ----------------
// blocks 0..127: GRU scan (bg = blk>>6 batch-group of 32, cb = blk&63 -> 16 h-cols).
//   Weights in REGISTERS (no weight LDS). Per-step compact h tile in hsC[t][bg][cb]
//   (sentinel 0xFF). Sync: 1-dword-per-tile probe issued at END of previous step,
//   checked after phase1; full payload loaded once + sentinel-verified.
// blocks 128..255: emissions, pipelined behind the scan via the same sentinel poll.
__global__ __launch_bounds__(256, 1) void fused(
    const USH* __restrict__ xeb, const USH* __restrict__ wihB, const USH* __restrict__ whhB,
    const float* __restrict__ bih, const float* __restrict__ bhh, char* __restrict__ hsC,
    const USH* __restrict__ fcwB, const float* __restrict__ fcb, float* __restrict__ em)
{
  __shared__ float redS[6144];   // 24KB reduction
  __shared__ USH  trpS[512];     // 1KB h transpose

  const int tid = threadIdx.x;
  const int wv = tid >> 6, ln = tid & 63;
  const int l16 = ln & 15, lq = ln >> 4;
  const v4f z4 = {0.f, 0.f, 0.f, 0.f};

  if (blockIdx.x < NSCAN) {
    // ================= scan role =================
    const int bg = blockIdx.x >> 6, cb = blockIdx.x & 63;
    const int b0 = bg * 32, c0 = cb * 16;

    // weights -> registers (one-time scattered loads)
    v8bf wihf[4][3], whhf[8][3];
    #pragma unroll
    for (int kt = 0; kt < 4; ++kt)
      #pragma unroll
      for (int g = 0; g < 3; ++g)
        wihf[kt][g] = ldb8(wihB + (size_t)(g * H_ + c0 + l16) * E_ + (wv * 16 + kt * 4 + lq) * 8);
    #pragma unroll
    for (int kt = 0; kt < 8; ++kt)
      #pragma unroll
      for (int g = 0; g < 3; ++g)
        whhf[kt][g] = ldb8(whhB + (size_t)(g * H_ + c0 + l16) * H_ + (wv * 32 + kt * 4 + lq) * 8);

    const int cgl = c0 + l16;
    const float bir = bih[cgl], biz = bih[H_ + cgl], bin = bih[2 * H_ + cgl];
    const float bhr = bhh[cgl], bhz = bhh[H_ + cgl], bhn = bhh[2 * H_ + cgl];

    const USH* a1b = xeb + (size_t)(b0 + l16) * (T_ * E_) + wv * 128 + 8 * lq;
    const u64 hC = (u64)(uintptr_t)hsC + (u64)bg * 65536;
    const int lane_off = (wv * 16 + (lq >> 1)) * 1024 + l16 * 32 + (lq & 1) * 16;
    const u64 probe_off = (u64)((wv * 16 + l16) * 1024 + 1020);  // last dword of tile (coalesced across lq)

    float hp0 = 0.f, hp1 = 0.f, hp2 = 0.f, hp3 = 0.f;  // waves 0/1: running h (4 batches/lane)
    v4f* rv = reinterpret_cast<v4f*>(redS);

    // prefetch xe for t=0
    uint4 pf[8];
    #pragma unroll
    for (int kt = 0; kt < 4; ++kt) {
      pf[kt * 2]     = *reinterpret_cast<const uint4*>(a1b + kt * 32);
      pf[kt * 2 + 1] = *reinterpret_cast<const uint4*>(a1b + 16 * (T_ * E_) + kt * 32);
    }
    u32 pr = 0;

    for (int t = 0; t < T_; ++t) {
      v4f acc[8];  // 0/1:R(m0,m1) 2/3:Z 4/5:NI 6/7:NH
      #pragma unroll
      for (int i = 0; i < 8; ++i) acc[i] = z4;

      // ---- phase 1: xe_t @ w_ih^T (regs only) ----
      #pragma unroll
      for (int kt = 0; kt < 4; ++kt) {
        v8bf a0 = __builtin_bit_cast(v8bf, pf[kt * 2]);
        v8bf a1f = __builtin_bit_cast(v8bf, pf[kt * 2 + 1]);
        acc[0] = MF(a0, wihf[kt][0], acc[0]); acc[1] = MF(a1f, wihf[kt][0], acc[1]);
        acc[2] = MF(a0, wihf[kt][1], acc[2]); acc[3] = MF(a1f, wihf[kt][1], acc[3]);
        acc[4] = MF(a0, wihf[kt][2], acc[4]); acc[5] = MF(a1f, wihf[kt][2], acc[5]);
      }

      if (t > 0) {
        const u64 hbase = hC + (u64)(t - 1) * 131072;
        // ---- probe check (probe was issued at end of previous step) ----
        while (true) {
          asm volatile("s_waitcnt vmcnt(0)" ::: "memory");
          __builtin_amdgcn_sched_barrier(0);
          if (__ballot(pr != 0xFFFFFFFFu) == ~0ull) break;
          asm volatile("global_load_dword %0, %1, off sc0 sc1" : "=v"(pr) : "v"(hbase + probe_off));
        }
        // ---- payload: 16 coalesced 16B coherent loads, sentinel-verified ----
        v4u ha[16];
        while (true) {
          #pragma unroll
          for (int kt = 0; kt < 8; ++kt) {
            ha[kt * 2]     = ldc16(hbase + lane_off + kt * 2048);
            ha[kt * 2 + 1] = ldc16(hbase + lane_off + kt * 2048 + 512);
          }
          asm volatile("s_waitcnt vmcnt(0)" ::: "memory");
          __builtin_amdgcn_sched_barrier(0);
          bool bad = false;
          #pragma unroll
          for (int f = 0; f < 16; ++f) {
            #pragma unroll
            for (int d = 0; d < 4; ++d) bad |= (ha[f][d] == 0xFFFFFFFFu);
          }
          if (__ballot(bad) == 0ull) break;
        }
        // ---- phase 2: h_{t-1} @ w_hh^T (regs only) ----
        #pragma unroll
        for (int kt = 0; kt < 8; ++kt) {
          v8bf a0 = __builtin_bit_cast(v8bf, ha[kt * 2]);
          v8bf a1f = __builtin_bit_cast(v8bf, ha[kt * 2 + 1]);
          acc[0] = MF(a0, whhf[kt][0], acc[0]); acc[1] = MF(a1f, whhf[kt][0], acc[1]);
          acc[2] = MF(a0, whhf[kt][1], acc[2]); acc[3] = MF(a1f, whhf[kt][1], acc[3]);
          acc[6] = MF(a0, whhf[kt][2], acc[6]); acc[7] = MF(a1f, whhf[kt][2], acc[7]);
        }
      }

      // ---- single-round cross-wave reduction (24KB), 1 sync ----
      if (wv >= 2) {
        #pragma unroll
        for (int f = 0; f < 8; ++f) rv[(wv - 2) * 512 + f * 64 + ln] = acc[f];
      } else if (wv == 0) {
        #pragma unroll
        for (int j = 0; j < 4; ++j) rv[1024 + j * 64 + ln] = acc[2 * j + 1];  // its mm=1 slices
      } else {
        #pragma unroll
        for (int j = 0; j < 4; ++j) rv[1280 + j * 64 + ln] = acc[2 * j];      // its mm=0 slices
      }
      __syncthreads();

      if (wv < 2) {
        v4f m0, m1, m2, m3;
        if (wv == 0) {
          m0 = acc[0]; m1 = acc[2]; m2 = acc[4]; m3 = acc[6];
          #pragma unroll
          for (int w = 0; w < 2; ++w) {
            m0 += rv[w * 512 + 0 * 64 + ln]; m1 += rv[w * 512 + 2 * 64 + ln];
            m2 += rv[w * 512 + 4 * 64 + ln]; m3 += rv[w * 512 + 6 * 64 + ln];
          }
          m0 += rv[1280 + 0 * 64 + ln]; m1 += rv[1280 + 1 * 64 + ln];
          m2 += rv[1280 + 2 * 64 + ln]; m3 += rv[1280 + 3 * 64 + ln];
        } else {
          m0 = acc[1]; m1 = acc[3]; m2 = acc[5]; m3 = acc[7];
          #pragma unroll
          for (int w = 0; w < 2; ++w) {
            m0 += rv[w * 512 + 1 * 64 + ln]; m1 += rv[w * 512 + 3 * 64 + ln];
            m2 += rv[w * 512 + 5 * 64 + ln]; m3 += rv[w * 512 + 7 * 64 + ln];
          }
          m0 += rv[1024 + 0 * 64 + ln]; m1 += rv[1024 + 1 * 64 + ln];
          m2 += rv[1024 + 2 * 64 + ln]; m3 += rv[1024 + 3 * 64 + ln];
        }
        // ---- gates (wave wv owns batch half mm=wv) ----
        #pragma unroll
        for (int r4 = 0; r4 < 4; ++r4) {
          float rg = sigm(m0[r4] + bir + bhr);
          float zg = sigm(m1[r4] + biz + bhz);
          float ng = tanhx(m2[r4] + bin + rg * (m3[r4] + bhn));
          float hprev = (r4 == 0 ? hp0 : r4 == 1 ? hp1 : r4 == 2 ? hp2 : hp3);
          float hn = (1.f - zg) * ng + zg * hprev;
          if (r4 == 0) hp0 = hn; else if (r4 == 1) hp1 = hn; else if (r4 == 2) hp2 = hn; else hp3 = hn;
          trpS[(wv * 16 + lq * 4 + r4) * 16 + l16] = f2b(hn);
        }
        // readback own rows, store half-tile (512B per wave)
        if (ln < 32) {
          v4u hv = *reinterpret_cast<const v4u*>(trpS + wv * 256 + ln * 8);
          stc16(hC + (u64)t * 131072 + (u64)cb * 1024 + (u64)(wv * 512) + (u64)ln * 16, hv);
        }
      }

      // ---- issue NEXT-step probe (h_t readiness), then xe prefetch ----
      {
        const u64 hb = hC + (u64)t * 131072;
        asm volatile("global_load_dword %0, %1, off sc0 sc1" : "=v"(pr) : "v"(hb + probe_off));
        const USH* a1n = a1b + (size_t)(t + 1 < T_ ? t + 1 : t) * E_;
        #pragma unroll
        for (int kt = 0; kt < 4; ++kt) {
          pf[kt * 2]     = *reinterpret_cast<const uint4*>(a1n + kt * 32);
          pf[kt * 2 + 1] = *reinterpret_cast<const uint4*>(a1n + 16 * (T_ * E_) + kt * 32);
        }
      }
    }
  } else {
    // ================= emission role =================
    const int e = blockIdx.x - NSCAN;
    // hoist fc_w fragments
    v8bf fcf[8][4];
    #pragma unroll
    for (int kt = 0; kt < 8; ++kt)
      #pragma unroll
      for (int nt = 0; nt < 4; ++nt)
        fcf[kt][nt] = ldb8(fcwB + (size_t)(nt * 16 + l16) * H_ + wv * 256 + kt * 32 + 8 * lq);
    float bias[4];
    #pragma unroll
    for (int nt = 0; nt < 4; ++nt) bias[nt] = fcb[nt * 16 + l16];

    v4f* rvE = reinterpret_cast<v4f*>(redS);
    for (int i = 0; i < 16; ++i) {
      int tile = i * 128 + e, t = tile >> 2, bq = tile & 3;
      const u64 ab = (u64)(uintptr_t)hsC + (u64)t * 131072 + (u64)(bq >> 1) * 65536
                   + (u64)((bq & 1) * 16 + l16) * 32 + (u64)(wv * 16 + (lq >> 1)) * 1024 + (u64)(lq & 1) * 16;
      v4u ha[8];
      while (true) {
        #pragma unroll
        for (int kt = 0; kt < 8; ++kt) ha[kt] = ldc16(ab + kt * 2048);
        asm volatile("s_waitcnt vmcnt(0)" ::: "memory");
        __builtin_amdgcn_sched_barrier(0);
        bool bad = false;
        #pragma unroll
        for (int kt = 0; kt < 8; ++kt) {
          #pragma unroll
          for (int d = 0; d < 4; ++d) bad |= (ha[kt][d] == 0xFFFFFFFFu);
        }
        if (__ballot(bad) == 0ull) break;
        __builtin_amdgcn_s_sleep(32);
      }
      v4f acc[4];
      #pragma unroll
      for (int nt = 0; nt < 4; ++nt) acc[nt] = z4;
      #pragma unroll
      for (int kt = 0; kt < 8; ++kt) {
        v8bf a = __builtin_bit_cast(v8bf, ha[kt]);
        #pragma unroll
        for (int nt = 0; nt < 4; ++nt) acc[nt] = MF(a, fcf[kt][nt], acc[nt]);
      }
      __syncthreads();
      if (wv != 0) {
        #pragma unroll
        for (int nt = 0; nt < 4; ++nt) rvE[(wv - 1) * 256 + nt * 64 + ln] = acc[nt];
      }
      __syncthreads();
      if (wv == 0) {
        #pragma unroll
        for (int nt = 0; nt < 4; ++nt) {
          v4f s = acc[nt];
          #pragma unroll
          for (int w = 0; w < 3; ++w) s += rvE[w * 256 + nt * 64 + ln];
          int k = nt * 16 + l16;
          #pragma unroll
          for (int r = 0; r < 4; ++r) {
            int b = bq * 16 + lq * 4 + r;
            em[((size_t)b * T_ + t) * 64 + k] = s[r] + bias[nt];
          }
        }
      }
    }
  }
}

// ---------------- CRF NLL per batch element ----------------
__global__ __launch_bounds__(64) void crfk(const float* __restrict__ em, const int* __restrict__ tags,
                                           const float* __restrict__ st, const float* __restrict__ en,
                                           const float* __restrict__ tr, float* __restrict__ res) {
  int b = blockIdx.x, j = threadIdx.x;
  __shared__ float trs[4096];
  for (int i = j; i < 4096; i += 64) trs[i] = tr[i];
  __syncthreads();
  const int* tg = tags + b * T_;
  const float* e = em + (long)b * T_ * 64;
  float np = 0.f;
  for (int t = j; t < T_; t += 64) {
    int ct = tg[t];
    np += e[t * 64 + ct];
    if (t > 0) np += trs[tg[t - 1] * 64 + ct];
  }
  #pragma unroll
  for (int o = 32; o; o >>= 1) np += __shfl_xor(np, o, 64);
  float num = np + st[tg[0]] + en[tg[T_ - 1]];
  float alpha = st[j] + e[j];
  for (int t = 1; t < T_; ++t) {
    float vv[64];
    #pragma unroll
    for (int i = 0; i < 64; ++i) vv[i] = __shfl(alpha, i, 64) + trs[i * 64 + j];
    float mc[4];
    #pragma unroll
    for (int c = 0; c < 4; ++c) {
      mc[c] = vv[c * 16];
      #pragma unroll
      for (int ii = 1; ii < 16; ++ii) mc[c] = fmaxf(mc[c], vv[c * 16 + ii]);
    }
    float M = fmaxf(fmaxf(mc[0], mc[1]), fmaxf(mc[2], mc[3]));
    float sc[4] = {0.f, 0.f, 0.f, 0.f};
    #pragma unroll
    for (int c = 0; c < 4; ++c)
      #pragma unroll
      for (int ii = 0; ii < 16; ++ii) sc[c] += __expf(vv[c * 16 + ii] - M);
    alpha = M + __logf((sc[0] + sc[1]) + (sc[2] + sc[3])) + e[t * 64 + j];
  }
  float v = alpha + en[j];
  float mm = v;
  #pragma unroll
  for (int o = 32; o; o >>= 1) mm = fmaxf(mm, __shfl_xor(mm, o, 64));
  float ss = __expf(v - mm);
  #pragma unroll
  for (int o = 32; o; o >>= 1) ss += __shfl_xor(ss, o, 64);
  if (j == 0) res[b] = (mm + __logf(ss)) - num;
}

__global__ void fin(const float* __restrict__ res, float* __restrict__ out) {
  float v = res[threadIdx.x];
  #pragma unroll
  for (int o = 32; o; o >>= 1) v += __shfl_xor(v, o, 64);
  if (threadIdx.x == 0) out[0] = v;
}

extern "C" void kernel_launch(void* const* d_in, const int* in_sizes, int n_in,
                              void* d_out, int out_size, void* d_ws, size_t ws_size,
                              hipStream_t stream) {
  (void)in_sizes; (void)n_in; (void)out_size;
  const int*   x    = (const int*)d_in[0];
  const int*   tags = (const int*)d_in[1];
  const float* emb  = (const float*)d_in[2];
  const float* wih  = (const float*)d_in[3];
  const float* whh  = (const float*)d_in[4];
  const float* bih  = (const float*)d_in[5];
  const float* bhh  = (const float*)d_in[6];
  const float* fcw  = (const float*)d_in[7];
  const float* fcb  = (const float*)d_in[8];
  const float* str  = (const float*)d_in[9];
  const float* enr  = (const float*)d_in[10];
  const float* trn  = (const float*)d_in[11];

  char* ws = (char*)d_ws;
  USH*   xeb  = (USH*)(ws + 0);           // 33,554,432
  USH*   wihB = (USH*)(ws + 33554432);    //  3,145,728
  USH*   whhB = (USH*)(ws + 36700160);    //  6,291,456
  USH*   fcwB = (USH*)(ws + 42991616);    //    131,072
  char*  hsC  = (char*)(ws + 43122688);   // 67,108,864: [t][group][cb][row][col] compact h stream
  float* em   = (float*)(ws + 110231552); //  8,388,608 ([B][T][64] f32)
  float* res  = (float*)(ws + 118620160); //        256
  if (ws_size < 118620416ull) return;

  // sentinel-fill the h stream (data-is-the-flag); runs every call / every replay
  hipMemsetAsync(hsC, 0xFF, 67108864, stream);

  castk<<<1536, 256, 0, stream>>>(wih, wihB, 3 * H_ * E_);
  castk<<<3072, 256, 0, stream>>>(whh, whhB, 3 * H_ * H_);
  castk<<<64, 256, 0, stream>>>(fcw, fcwB, 64 * H_);
  gatherk<<<B_ * T_, 128, 0, stream>>>(x, emb, xeb);
  fused<<<256, 256, 0, stream>>>(xeb, wihB, whhB, bih, bhh, hsC, fcwB, fcb, em);
  crfk<<<B_, 64, 0, stream>>>(em, tags, str, enr, trn, res);
  fin<<<1, 64, 0, stream>>>(res, (float*)d_out);
}